// Round 4
// baseline (352.581 us; speedup 1.0000x reference)
//
#include <hip/hip_runtime.h>
#include <hip/hip_bf16.h>

#define NN 8192      // nodes
#define NE 32768     // edges
#define FD 16        // features
#define DIM 64
#define BT 4
#define RANK 512

typedef __attribute__((ext_vector_type(8))) short bf16x8;
typedef __attribute__((ext_vector_type(4))) float f32x4;

__device__ inline unsigned short f2bf(float f) {
    union { float f; unsigned u; } c; c.f = f;
    return (unsigned short)((c.u + 0x7fffu + ((c.u >> 16) & 1u)) >> 16);
}
__device__ inline float ubf(unsigned short h) {
    union { unsigned u; float f; } c; c.u = ((unsigned)h) << 16; return c.f;
}
__device__ inline float bflo(unsigned u) { union { unsigned u; float f; } c; c.u = u << 16; return c.f; }
__device__ inline float bfhi(unsigned u) { union { unsigned u; float f; } c; c.u = u & 0xffff0000u; return c.f; }

// ================================================================ prep0:
//   blocks [0,2048):    init s = relu(x@W0.T+b0), + bf16 hi/lo split, + c = s@b2
//   blocks [2048,2176): degree histograms (dst float, src int)
//   blocks [2176,6272): per-edge hidden h32 + bond argmax
__global__ __launch_bounds__(256) void k_prep0(
    const float* __restrict__ x, const int* __restrict__ ei, const float* __restrict__ ea,
    const float* __restrict__ W0, const float* __restrict__ b0,
    const float* __restrict__ nnW1, const float* __restrict__ nnb1, const float* __restrict__ b2,
    float* __restrict__ s, unsigned short* __restrict__ shi, unsigned short* __restrict__ slo,
    float* __restrict__ cbuf, float* __restrict__ deg, int* __restrict__ srccnt,
    float* __restrict__ h32, int* __restrict__ bond)
{
    int bid = blockIdx.x, tid = threadIdx.x;
    if (bid < 2048) {
        __shared__ float sm[4][64];
        int wid = tid >> 6, lane = tid & 63;
        int n = bid * 4 + wid;
        const float4* xr = (const float4*)(x + (size_t)n * FD);
        const float4* wr = (const float4*)(W0 + lane * FD);
        float4 x0 = xr[0], x1 = xr[1], x2 = xr[2], x3 = xr[3];
        float4 w0 = wr[0], w1 = wr[1], w2 = wr[2], w3 = wr[3];
        float acc = b0[lane]
            + x0.x*w0.x + x0.y*w0.y + x0.z*w0.z + x0.w*w0.w
            + x1.x*w1.x + x1.y*w1.y + x1.z*w1.z + x1.w*w1.w
            + x2.x*w2.x + x2.y*w2.y + x2.z*w2.z + x2.w*w2.w
            + x3.x*w3.x + x3.y*w3.y + x3.z*w3.z + x3.w*w3.w;
        float sv = fmaxf(acc, 0.f);
        size_t idx = (size_t)n * DIM + lane;
        s[idx] = sv;
        unsigned short h = f2bf(sv);
        shi[idx] = h; slo[idx] = f2bf(sv - ubf(h));
        sm[wid][lane] = sv;
        __syncthreads();
        float cv = 0.f;
        for (int i = 0; i < 64; ++i) cv += sm[wid][i] * b2[i * 64 + lane];
        cbuf[idx] = cv;
    } else if (bid < 2176) {
        int e = (bid - 2048) * 256 + tid;
        atomicAdd(&deg[ei[NE + e]], 1.0f);
        atomicAdd(&srccnt[ei[e]], 1);
    } else {
        int e = (bid - 2176) * 8 + (tid >> 5);
        int k = tid & 31;
        float a0 = ea[e * 4 + 0], a1 = ea[e * 4 + 1], a2 = ea[e * 4 + 2], a3 = ea[e * 4 + 3];
        float h = nnb1[k] + a0 * nnW1[k * 4 + 0] + a1 * nnW1[k * 4 + 1]
                          + a2 * nnW1[k * 4 + 2] + a3 * nnW1[k * 4 + 3];
        h32[e * 32 + k] = fmaxf(h, 0.f);
        if (k == 0) {
            int bi = 0; float bv = a0;
            if (a1 > bv) { bv = a1; bi = 1; }
            if (a2 > bv) { bv = a2; bi = 2; }
            if (a3 > bv) { bv = a3; bi = 3; }
            bond[e] = bi;
        }
    }
}

// ================================================================ prep1:
//   blocks [0,512):   W2T[col][i] = W2[(i*64+col>>5)*32 + col&31], bf16 hi/lo
//   blocks [512,560): GRU weight transpose WT[i][go]
//   blocks [560,816): M[b] = V[b]@U[b]
__global__ __launch_bounds__(256) void k_prep1(
    const float* __restrict__ W2, const float* __restrict__ Wih, const float* __restrict__ Whh,
    const float* __restrict__ U, const float* __restrict__ V,
    unsigned short* __restrict__ wh, unsigned short* __restrict__ wl,
    float* __restrict__ WihT, float* __restrict__ WhhT, float* __restrict__ M)
{
    int bid = blockIdx.x, tid = threadIdx.x;
    if (bid < 512) {
        int gid = bid * 256 + tid;          // gid = col*64 + i
        int col = gid >> 6, i = gid & 63;
        float v = W2[(size_t)(i * 64 + (col >> 5)) * 32 + (col & 31)];
        unsigned short h = f2bf(v);
        wh[gid] = h; wl[gid] = f2bf(v - ubf(h));
    } else if (bid < 560) {
        int gid = (bid - 512) * 256 + tid;  // 12288 total
        int i = gid / 192, go = gid % 192;
        WihT[gid] = Wih[go * 64 + i];
        WhhT[gid] = Whh[go * 64 + i];
    } else {
        __shared__ float red[4][64];
        int t = bid - 560;
        int b = t >> 6, d = t & 63;
        int chunk = tid >> 6, dp = tid & 63;
        const float* Vp = V + ((size_t)b * DIM + d) * RANK;
        const float* Up = U + (size_t)b * RANK * DIM;
        float acc = 0.f;
        for (int r = chunk * 128; r < chunk * 128 + 128; ++r)
            acc += Vp[r] * Up[(size_t)r * DIM + dp];
        red[chunk][dp] = acc;
        __syncthreads();
        if (chunk == 0)
            M[((size_t)b * DIM + d) * DIM + dp] =
                red[0][dp] + red[1][dp] + red[2][dp] + red[3][dp];
    }
}

// ================================================================ CSR: exclusive scan of src counts
__global__ __launch_bounds__(1024) void k_scan(const int* __restrict__ cnt,
                                               int* __restrict__ start, int* __restrict__ cursor) {
    __shared__ int ls[1024];
    int tid = threadIdx.x;
    int v[8], tot = 0;
#pragma unroll
    for (int j = 0; j < 8; ++j) { v[j] = cnt[tid * 8 + j]; tot += v[j]; }
    ls[tid] = tot;
    __syncthreads();
    for (int off = 1; off < 1024; off <<= 1) {
        int t = (tid >= off) ? ls[tid - off] : 0;
        __syncthreads();
        ls[tid] += t;
        __syncthreads();
    }
    int run = ls[tid] - tot;   // exclusive base
#pragma unroll
    for (int j = 0; j < 8; ++j) {
        start[tid * 8 + j] = run; cursor[tid * 8 + j] = run; run += v[j];
    }
}

__global__ __launch_bounds__(256) void k_scatter(const int* __restrict__ ei,
                                                 int* __restrict__ cursor, int* __restrict__ eord) {
    int e = blockIdx.x * 256 + threadIdx.x;
    int pos = atomicAdd(&cursor[ei[e]], 1);
    eord[pos] = e;
}

// ================================================================ A = s @ W2  via split-bf16 MFMA
// M=8192 N=2048 K=64. Block: 4 waves, each 64x64 tile; tile 64M x 256N.
__global__ __launch_bounds__(256) void k_gemm_A(const unsigned short* __restrict__ sh,
                                                const unsigned short* __restrict__ sl,
                                                const unsigned short* __restrict__ wh,
                                                const unsigned short* __restrict__ wl,
                                                unsigned short* __restrict__ A) {
    int tid = threadIdx.x, wid = tid >> 6, lane = tid & 63;
    int lr = lane & 15, kg = lane >> 4;
    int m0 = blockIdx.x * 64;
    int n0 = blockIdx.y * 256 + wid * 64;
    f32x4 acc[4][4] = {};
#pragma unroll
    for (int kb = 0; kb < 64; kb += 32) {
        bf16x8 ah[4], al[4], bh[4], bl[4];
#pragma unroll
        for (int mi = 0; mi < 4; ++mi) {
            size_t off = (size_t)(m0 + mi * 16 + lr) * 64 + kb + kg * 8;
            ah[mi] = *(const bf16x8*)(sh + off);
            al[mi] = *(const bf16x8*)(sl + off);
        }
#pragma unroll
        for (int ni = 0; ni < 4; ++ni) {
            size_t off = (size_t)(n0 + ni * 16 + lr) * 64 + kb + kg * 8;
            bh[ni] = *(const bf16x8*)(wh + off);
            bl[ni] = *(const bf16x8*)(wl + off);
        }
#pragma unroll
        for (int mi = 0; mi < 4; ++mi)
#pragma unroll
            for (int ni = 0; ni < 4; ++ni) {
                acc[mi][ni] = __builtin_amdgcn_mfma_f32_16x16x32_bf16(ah[mi], bh[ni], acc[mi][ni], 0, 0, 0);
                acc[mi][ni] = __builtin_amdgcn_mfma_f32_16x16x32_bf16(ah[mi], bl[ni], acc[mi][ni], 0, 0, 0);
                acc[mi][ni] = __builtin_amdgcn_mfma_f32_16x16x32_bf16(al[mi], bh[ni], acc[mi][ni], 0, 0, 0);
            }
    }
    // C/D layout (m89-verified): col = lane&15, row = (lane>>4)*4 + reg
#pragma unroll
    for (int mi = 0; mi < 4; ++mi)
#pragma unroll
        for (int r = 0; r < 4; ++r) {
            size_t row = (size_t)(m0 + mi * 16 + kg * 4 + r) * 2048;
#pragma unroll
            for (int ni = 0; ni < 4; ++ni)
                A[row + n0 + ni * 16 + lr] = f2bf(acc[mi][ni][r]);
        }
}

// ================================================================ CSR edge message + scatter
// wave per src node; A row pinned in 16 VGPRs across all out-edges.
__global__ __launch_bounds__(256) void k_edge(const int* __restrict__ ei,
                                              const int* __restrict__ start,
                                              const int* __restrict__ srccnt,
                                              const int* __restrict__ eord,
                                              const float* __restrict__ h32,
                                              const unsigned short* __restrict__ A,
                                              const float* __restrict__ cbuf,
                                              float* __restrict__ agg) {
    int tid = threadIdx.x, wid = tid >> 6, o = tid & 63;
    int n = blockIdx.x * 4 + wid;
    int cnt = srccnt[n];
    if (cnt == 0) return;
    int beg = start[n];
    float cv = cbuf[(size_t)n * DIM + o];
    const uint4* Ap = (const uint4*)(A + (size_t)n * 2048 + o * 32);
    uint4 a0 = Ap[0], a1 = Ap[1], a2 = Ap[2], a3 = Ap[3];
    for (int i = beg; i < beg + cnt; ++i) {
        int e = eord[i];
        int dst = ei[NE + e];
        const float4* hp = (const float4*)(h32 + (size_t)e * 32);
        float acc = cv;
        float4 hA = hp[0], hB = hp[1];
        acc += hA.x*bflo(a0.x) + hA.y*bfhi(a0.x) + hA.z*bflo(a0.y) + hA.w*bfhi(a0.y)
             + hB.x*bflo(a0.z) + hB.y*bfhi(a0.z) + hB.z*bflo(a0.w) + hB.w*bfhi(a0.w);
        hA = hp[2]; hB = hp[3];
        acc += hA.x*bflo(a1.x) + hA.y*bfhi(a1.x) + hA.z*bflo(a1.y) + hA.w*bfhi(a1.y)
             + hB.x*bflo(a1.z) + hB.y*bfhi(a1.z) + hB.z*bflo(a1.w) + hB.w*bfhi(a1.w);
        hA = hp[4]; hB = hp[5];
        acc += hA.x*bflo(a2.x) + hA.y*bfhi(a2.x) + hA.z*bflo(a2.y) + hA.w*bfhi(a2.y)
             + hB.x*bflo(a2.z) + hB.y*bfhi(a2.z) + hB.z*bflo(a2.w) + hB.w*bfhi(a2.w);
        hA = hp[6]; hB = hp[7];
        acc += hA.x*bflo(a3.x) + hA.y*bfhi(a3.x) + hA.z*bflo(a3.y) + hA.w*bfhi(a3.y)
             + hB.x*bflo(a3.z) + hB.y*bfhi(a3.z) + hB.z*bflo(a3.w) + hB.w*bfhi(a3.w);
        atomicAdd(&agg[(size_t)dst * DIM + o], acc);
    }
}

// ================================================================ NNConv combine + GRU cell
// 16 nodes/block, 4 nodes/thread; epilogue: bf16 split + c = h@b2; self-zero agg.
__global__ __launch_bounds__(256) void k_update(float* __restrict__ s,
                                                unsigned short* __restrict__ shi,
                                                unsigned short* __restrict__ slo,
                                                float* __restrict__ cbuf,
                                                float* __restrict__ agg,
                                                const float* __restrict__ deg,
                                                const float* __restrict__ root,
                                                const float* __restrict__ conv_b,
                                                const float* __restrict__ WihT,
                                                const float* __restrict__ WhhT,
                                                const float* __restrict__ bih,
                                                const float* __restrict__ bhh,
                                                const float* __restrict__ b2) {
    __shared__ float sm_s[16][64];
    __shared__ float sm_m[16][64];
    int tid = threadIdx.x, w = tid >> 6, lane = tid & 63;
    int n0 = blockIdx.x * 16;
#pragma unroll
    for (int q = 0; q < 4; ++q) {
        int ln = w + q * 4;
        sm_s[ln][lane] = s[(size_t)(n0 + ln) * DIM + lane];
    }
    __syncthreads();
    float mval[4];
#pragma unroll
    for (int q = 0; q < 4; ++q) {
        int ln = w + q * 4, node = n0 + ln;
        size_t idx = (size_t)node * DIM + lane;
        float degc = fmaxf(deg[node], 1.f);
        mval[q] = agg[idx] / degc + conv_b[lane];
        agg[idx] = 0.f;                       // self-zero for next iteration
    }
    for (int i = 0; i < 64; ++i) {
        float rv = root[i * 64 + lane];
#pragma unroll
        for (int q = 0; q < 4; ++q) mval[q] += sm_s[w + q * 4][i] * rv;
    }
#pragma unroll
    for (int q = 0; q < 4; ++q) sm_m[w + q * 4][lane] = fmaxf(mval[q], 0.f);
    __syncthreads();
    float gr[4] = {}, gz[4] = {}, gn[4] = {}, hr[4] = {}, hz[4] = {}, hn[4] = {};
    for (int i = 0; i < 64; ++i) {
        float w0 = WihT[i * 192 + lane];
        float w1 = WihT[i * 192 + 64 + lane];
        float w2 = WihT[i * 192 + 128 + lane];
        float v0 = WhhT[i * 192 + lane];
        float v1 = WhhT[i * 192 + 64 + lane];
        float v2 = WhhT[i * 192 + 128 + lane];
#pragma unroll
        for (int q = 0; q < 4; ++q) {
            int ln = w + q * 4;
            float mi = sm_m[ln][i], hi = sm_s[ln][i];
            gr[q] += mi * w0; gz[q] += mi * w1; gn[q] += mi * w2;
            hr[q] += hi * v0; hz[q] += hi * v1; hn[q] += hi * v2;
        }
    }
    float bi0 = bih[lane], bi1 = bih[64 + lane], bi2 = bih[128 + lane];
    float bh0 = bhh[lane], bh1 = bhh[64 + lane], bh2 = bhh[128 + lane];
#pragma unroll
    for (int q = 0; q < 4; ++q) {
        int ln = w + q * 4, node = n0 + ln;
        float r = 1.f / (1.f + expf(-(gr[q] + bi0 + hr[q] + bh0)));
        float z = 1.f / (1.f + expf(-(gz[q] + bi1 + hz[q] + bh1)));
        float nv = tanhf(gn[q] + bi2 + r * (hn[q] + bh2));
        float hv = sm_s[ln][lane];
        float nh = (1.f - z) * nv + z * hv;
        size_t idx = (size_t)node * DIM + lane;
        s[idx] = nh;
        unsigned short hb = f2bf(nh);
        shi[idx] = hb; slo[idx] = f2bf(nh - ubf(hb));
        sm_m[ln][lane] = nh;                  // reuse sm_m for new h
    }
    __syncthreads();
#pragma unroll
    for (int q = 0; q < 4; ++q) {
        int ln = w + q * 4, node = n0 + ln;
        float cv = 0.f;
        for (int i = 0; i < 64; ++i) cv += sm_m[ln][i] * b2[i * 64 + lane];
        cbuf[(size_t)node * DIM + lane] = cv;
    }
}

// ================================================================ out_edges + out_combine
__global__ __launch_bounds__(256) void k_edges_out(const float* __restrict__ s,
                                                   const float* __restrict__ x,
                                                   const float* __restrict__ W1l,
                                                   const float* __restrict__ b1l,
                                                   const float* __restrict__ WUp,
                                                   const float* __restrict__ bUp,
                                                   float* __restrict__ oe,
                                                   float* __restrict__ oc) {
    __shared__ float sm_s[4][64];
    __shared__ float sm_oe[4][4];
    int tid = threadIdx.x, w = tid >> 6, lane = tid & 63;
    int node = blockIdx.x * 4 + w;
    float sv = s[(size_t)node * DIM + lane];
    sm_s[w][lane] = sv;
    __syncthreads();
    if (lane < 4) {
        float acc = b1l[lane];
        for (int i = 0; i < 64; ++i) acc += sm_s[w][i] * W1l[lane * 64 + i];
        acc = fmaxf(acc, 0.f);
        sm_oe[w][lane] = acc;
        oe[(size_t)node * 4 + lane] = acc;
    }
    __syncthreads();
    float ocv;
    if (x[(size_t)node * FD] == 2.0f) {
        ocv = bUp[lane];
#pragma unroll
        for (int t = 0; t < 4; ++t) ocv += sm_oe[w][t] * WUp[lane * 4 + t];
    } else {
        ocv = sv;
    }
    oc[(size_t)node * DIM + lane] = ocv;
}

// ================================================================ FGNet edge: me = oc[src] @ M[bond], scatter
__global__ __launch_bounds__(256) void k_fgedge(const int* __restrict__ ei,
                                                const int* __restrict__ bond,
                                                const float* __restrict__ oc,
                                                const float* __restrict__ M,
                                                float* __restrict__ fg_agg) {
    __shared__ float so[4][64];
    int tid = threadIdx.x, w = tid >> 6, lane = tid & 63;
    int e = blockIdx.x * 4 + w;
    int src = ei[e], dst = ei[NE + e];
    int b = bond[e];
    so[w][lane] = oc[(size_t)src * DIM + lane];
    __syncthreads();
    float acc = 0.f;
    const float* Mp = M + b * DIM * DIM;
    for (int d = 0; d < 64; ++d) acc += so[w][d] * Mp[d * 64 + lane];
    atomicAdd(&fg_agg[(size_t)dst * DIM + lane], acc);
}

// ================================================================ final: msg_f -> msg_to_edge -> out_edges -> log_softmax
__global__ __launch_bounds__(256) void k_final(const float* __restrict__ fg_agg,
                                               const float* __restrict__ deg,
                                               const float* __restrict__ oe,
                                               const float* __restrict__ WDown,
                                               const float* __restrict__ bDown,
                                               const float* __restrict__ weight_e,
                                               const float* __restrict__ linWe,
                                               const float* __restrict__ linbe,
                                               float* __restrict__ out) {
    int tid = threadIdx.x, w = tid >> 6, lane = tid & 63;
    int node = blockIdx.x * 4 + w;
    float degc = fmaxf(deg[node], 1.f);
    float mf = fmaxf(fg_agg[(size_t)node * DIM + lane] / degc, 0.f);
    float mte[4];
#pragma unroll
    for (int t = 0; t < 4; ++t) {
        float p = mf * WDown[t * 64 + lane];
#pragma unroll
        for (int off = 32; off; off >>= 1) p += __shfl_xor(p, off);
        mte[t] = p + bDown[t];
    }
    float val[4];
    float mx = -1e30f;
#pragma unroll
    for (int t = 0; t < 4; ++t) {
        float acc = linbe[t];
#pragma unroll
        for (int t2 = 0; t2 < 4; ++t2) acc += weight_e[t2] * mte[t2] * linWe[t * 4 + t2];
        val[t] = oe[(size_t)node * 4 + t] + fmaxf(acc, 0.f);
        mx = fmaxf(mx, val[t]);
    }
    float lse = 0.f;
#pragma unroll
    for (int t = 0; t < 4; ++t) lse += expf(val[t] - mx);
    lse = logf(lse);
    if (lane < 4) out[(size_t)node * 4 + lane] = val[lane] - mx - lse;
}

// ================================================================ host
extern "C" void kernel_launch(void* const* d_in, const int* in_sizes, int n_in,
                              void* d_out, int out_size, void* d_ws, size_t ws_size,
                              hipStream_t stream) {
    const float* x       = (const float*)d_in[0];
    const int*   ei      = (const int*)  d_in[1];
    const float* ea      = (const float*)d_in[2];
    const float* W0      = (const float*)d_in[3];
    const float* b0      = (const float*)d_in[4];
    const float* nnW1    = (const float*)d_in[5];
    const float* nnb1    = (const float*)d_in[6];
    const float* nnW2    = (const float*)d_in[7];
    const float* nnb2    = (const float*)d_in[8];
    const float* root    = (const float*)d_in[9];
    const float* conv_b  = (const float*)d_in[10];
    const float* Wih     = (const float*)d_in[11];
    const float* Whh     = (const float*)d_in[12];
    const float* bih     = (const float*)d_in[13];
    const float* bhh     = (const float*)d_in[14];
    const float* W1l     = (const float*)d_in[15];
    const float* b1l     = (const float*)d_in[16];
    const float* WUp     = (const float*)d_in[17];
    const float* bUp     = (const float*)d_in[18];
    const float* WDown   = (const float*)d_in[19];
    const float* bDown   = (const float*)d_in[20];
    const float* U       = (const float*)d_in[21];
    const float* V       = (const float*)d_in[22];
    // d_in[23..25] weight/linW/linb: dead code (node-'out' branch never reaches output)
    const float* weight_e= (const float*)d_in[26];
    const float* linWe   = (const float*)d_in[27];
    const float* linbe   = (const float*)d_in[28];
    float* out = (float*)d_out;

    char* ws = (char*)d_ws;
    size_t off = 0;
    auto alloc = [&](size_t bytes) { size_t o = off; off = (off + bytes + 255) & ~(size_t)255; return o; };
    // adjacency matters: deg+srccnt share one memset; agg+fg_agg share one memset
    float* deg    = (float*)(ws + alloc((size_t)NN * 4));            // 32KB
    int*   srccnt = (int*)  (ws + alloc((size_t)NN * 4));            // 32KB (adjacent)
    float* agg    = (float*)(ws + alloc((size_t)NN * DIM * 4));      // 2MB
    float* fg_agg = (float*)(ws + alloc((size_t)NN * DIM * 4));      // 2MB (adjacent)
    float* s      = (float*)(ws + alloc((size_t)NN * DIM * 4));
    unsigned short* shi = (unsigned short*)(ws + alloc((size_t)NN * DIM * 2));
    unsigned short* slo = (unsigned short*)(ws + alloc((size_t)NN * DIM * 2));
    float* cbuf   = (float*)(ws + alloc((size_t)NN * DIM * 4));
    float* h32    = (float*)(ws + alloc((size_t)NE * 32 * 4));
    int*   bond   = (int*)  (ws + alloc((size_t)NE * 4));
    int*   startp = (int*)  (ws + alloc((size_t)NN * 4));
    int*   cursor = (int*)  (ws + alloc((size_t)NN * 4));
    int*   eord   = (int*)  (ws + alloc((size_t)NE * 4));
    float* oe     = (float*)(ws + alloc((size_t)NN * 4 * 4));
    float* oc     = (float*)(ws + alloc((size_t)NN * DIM * 4));
    float* Mbuf   = (float*)(ws + alloc((size_t)BT * DIM * DIM * 4));
    float* WihT   = (float*)(ws + alloc((size_t)64 * 192 * 4));
    float* WhhT   = (float*)(ws + alloc((size_t)64 * 192 * 4));
    unsigned short* w2h = (unsigned short*)(ws + alloc((size_t)2048 * 64 * 2));
    unsigned short* w2l = (unsigned short*)(ws + alloc((size_t)2048 * 64 * 2));
    unsigned short* Abuf = (unsigned short*)(ws + alloc((size_t)NN * 2048 * 2));
    (void)n_in; (void)in_sizes; (void)out_size; (void)ws_size;

    hipMemsetAsync(deg, 0, (size_t)2 * NN * 4, stream);              // deg + srccnt
    hipMemsetAsync(agg, 0, (size_t)2 * NN * DIM * 4, stream);        // agg + fg_agg

    k_prep0<<<6272, 256, 0, stream>>>(x, ei, ea, W0, b0, nnW1, nnb1, nnb2,
                                      s, shi, slo, cbuf, deg, srccnt, h32, bond);
    k_prep1<<<816, 256, 0, stream>>>(nnW2, Wih, Whh, U, V, w2h, w2l, WihT, WhhT, Mbuf);
    k_scan<<<1, 1024, 0, stream>>>(srccnt, startp, cursor);
    k_scatter<<<NE / 256, 256, 0, stream>>>(ei, cursor, eord);

    for (int it = 0; it < 3; ++it) {
        k_gemm_A<<<dim3(NN / 64, 2048 / 256), 256, 0, stream>>>(shi, slo, w2h, w2l, Abuf);
        k_edge<<<NN / 4, 256, 0, stream>>>(ei, startp, srccnt, eord, h32, Abuf, cbuf, agg);
        k_update<<<NN / 16, 256, 0, stream>>>(s, shi, slo, cbuf, agg, deg, root, conv_b,
                                              WihT, WhhT, bih, bhh, nnb2);
    }

    k_edges_out<<<NN / 4, 256, 0, stream>>>(s, x, W1l, b1l, WUp, bUp, oe, oc);
    k_fgedge<<<NE / 4, 256, 0, stream>>>(ei, bond, oc, Mbuf, fg_agg);
    k_final<<<NN / 4, 256, 0, stream>>>(fg_agg, deg, oe, WDown, bDown, weight_e, linWe, linbe, out);
}

// Round 5
// 297.859 us; speedup vs baseline: 1.1837x; 1.1837x over previous
//
#include <hip/hip_runtime.h>
#include <hip/hip_bf16.h>

#define NN 8192      // nodes
#define NE 32768     // edges
#define FD 16        // features
#define DIM 64
#define BT 4
#define RANK 512

typedef __attribute__((ext_vector_type(8))) short bf16x8;
typedef __attribute__((ext_vector_type(4))) float f32x4;

__device__ inline unsigned short f2bf(float f) {
    union { float f; unsigned u; } c; c.f = f;
    return (unsigned short)((c.u + 0x7fffu + ((c.u >> 16) & 1u)) >> 16);
}
__device__ inline float ubf(unsigned short h) {
    union { unsigned u; float f; } c; c.u = ((unsigned)h) << 16; return c.f;
}
__device__ inline float bflo(unsigned u) { union { unsigned u; float f; } c; c.u = u << 16; return c.f; }
__device__ inline float bfhi(unsigned u) { union { unsigned u; float f; } c; c.u = u & 0xffff0000u; return c.f; }

// ================================================================ prep0:
//   blocks [0,2048):    init s = relu(x@W0.T+b0), + bf16 hi/lo split, + c = s@b2
//   blocks [2048,2176): degree histograms (dst float, src int)
//   blocks [2176,6272): per-edge hidden h32 + bond argmax
__global__ __launch_bounds__(256) void k_prep0(
    const float* __restrict__ x, const int* __restrict__ ei, const float* __restrict__ ea,
    const float* __restrict__ W0, const float* __restrict__ b0,
    const float* __restrict__ nnW1, const float* __restrict__ nnb1, const float* __restrict__ b2,
    float* __restrict__ s, unsigned short* __restrict__ shi, unsigned short* __restrict__ slo,
    float* __restrict__ cbuf, float* __restrict__ deg, int* __restrict__ srccnt,
    float* __restrict__ h32, int* __restrict__ bond)
{
    int bid = blockIdx.x, tid = threadIdx.x;
    if (bid < 2048) {
        __shared__ float sm[4][64];
        int wid = tid >> 6, lane = tid & 63;
        int n = bid * 4 + wid;
        const float4* xr = (const float4*)(x + (size_t)n * FD);
        const float4* wr = (const float4*)(W0 + lane * FD);
        float4 x0 = xr[0], x1 = xr[1], x2 = xr[2], x3 = xr[3];
        float4 w0 = wr[0], w1 = wr[1], w2 = wr[2], w3 = wr[3];
        float acc = b0[lane]
            + x0.x*w0.x + x0.y*w0.y + x0.z*w0.z + x0.w*w0.w
            + x1.x*w1.x + x1.y*w1.y + x1.z*w1.z + x1.w*w1.w
            + x2.x*w2.x + x2.y*w2.y + x2.z*w2.z + x2.w*w2.w
            + x3.x*w3.x + x3.y*w3.y + x3.z*w3.z + x3.w*w3.w;
        float sv = fmaxf(acc, 0.f);
        size_t idx = (size_t)n * DIM + lane;
        s[idx] = sv;
        unsigned short h = f2bf(sv);
        shi[idx] = h; slo[idx] = f2bf(sv - ubf(h));
        sm[wid][lane] = sv;
        __syncthreads();
        float cv = 0.f;
        for (int i = 0; i < 64; ++i) cv += sm[wid][i] * b2[i * 64 + lane];
        cbuf[idx] = cv;
    } else if (bid < 2176) {
        int e = (bid - 2048) * 256 + tid;
        atomicAdd(&deg[ei[NE + e]], 1.0f);
        atomicAdd(&srccnt[ei[e]], 1);
    } else {
        int e = (bid - 2176) * 8 + (tid >> 5);
        int k = tid & 31;
        float a0 = ea[e * 4 + 0], a1 = ea[e * 4 + 1], a2 = ea[e * 4 + 2], a3 = ea[e * 4 + 3];
        float h = nnb1[k] + a0 * nnW1[k * 4 + 0] + a1 * nnW1[k * 4 + 1]
                          + a2 * nnW1[k * 4 + 2] + a3 * nnW1[k * 4 + 3];
        h32[e * 32 + k] = fmaxf(h, 0.f);
        if (k == 0) {
            int bi = 0; float bv = a0;
            if (a1 > bv) { bv = a1; bi = 1; }
            if (a2 > bv) { bv = a2; bi = 2; }
            if (a3 > bv) { bv = a3; bi = 3; }
            bond[e] = bi;
        }
    }
}

// ================================================================ prep1:
//   blocks [0,512):   W2T bf16 hi/lo:  wh/wl[col*64+i] = split(W2[(i*64+col>>5)*32 + col&31])
//   blocks [512,560): GRU weight pack Wpk[i*192+go] = {Wih[go][i], Whh[go][i]}
//   blocks [560,816): M[b] = V[b]@U[b]
__global__ __launch_bounds__(256) void k_prep1(
    const float* __restrict__ W2, const float* __restrict__ Wih, const float* __restrict__ Whh,
    const float* __restrict__ U, const float* __restrict__ V,
    unsigned short* __restrict__ wh, unsigned short* __restrict__ wl,
    float2* __restrict__ Wpk, float* __restrict__ M)
{
    int bid = blockIdx.x, tid = threadIdx.x;
    if (bid < 512) {
        int gid = bid * 256 + tid;          // gid = col*64 + i
        int col = gid >> 6, i = gid & 63;
        float v = W2[(size_t)(i * 64 + (col >> 5)) * 32 + (col & 31)];
        unsigned short h = f2bf(v);
        wh[gid] = h; wl[gid] = f2bf(v - ubf(h));
    } else if (bid < 560) {
        int gid = (bid - 512) * 256 + tid;  // 12288 total: gid = i*192 + go
        int i = gid / 192, go = gid % 192;
        Wpk[gid] = make_float2(Wih[go * 64 + i], Whh[go * 64 + i]);
    } else {
        __shared__ float red[4][64];
        int t = bid - 560;
        int b = t >> 6, d = t & 63;
        int chunk = tid >> 6, dp = tid & 63;
        const float* Vp = V + ((size_t)b * DIM + d) * RANK;
        const float* Up = U + (size_t)b * RANK * DIM;
        float acc = 0.f;
        for (int r = chunk * 128; r < chunk * 128 + 128; ++r)
            acc += Vp[r] * Up[(size_t)r * DIM + dp];
        red[chunk][dp] = acc;
        __syncthreads();
        if (chunk == 0)
            M[((size_t)b * DIM + d) * DIM + dp] =
                red[0][dp] + red[1][dp] + red[2][dp] + red[3][dp];
    }
}

// ================================================================ CSR: exclusive scan of src counts
__global__ __launch_bounds__(1024) void k_scan(const int* __restrict__ cnt,
                                               int* __restrict__ start, int* __restrict__ cursor) {
    __shared__ int ls[1024];
    int tid = threadIdx.x;
    int v[8], tot = 0;
#pragma unroll
    for (int j = 0; j < 8; ++j) { v[j] = cnt[tid * 8 + j]; tot += v[j]; }
    ls[tid] = tot;
    __syncthreads();
    for (int off = 1; off < 1024; off <<= 1) {
        int t = (tid >= off) ? ls[tid - off] : 0;
        __syncthreads();
        ls[tid] += t;
        __syncthreads();
    }
    int run = ls[tid] - tot;   // exclusive base
#pragma unroll
    for (int j = 0; j < 8; ++j) {
        start[tid * 8 + j] = run; cursor[tid * 8 + j] = run; run += v[j];
    }
}

__global__ __launch_bounds__(256) void k_scatter(const int* __restrict__ ei,
                                                 int* __restrict__ cursor, int* __restrict__ eord) {
    int e = blockIdx.x * 256 + threadIdx.x;
    int pos = atomicAdd(&cursor[ei[e]], 1);
    eord[pos] = e;
}

// ================================================================ A = s @ W2  via split-bf16 MFMA
// M=8192 N=2048 K=64. Block: 4 waves, each 64x64 tile; tile 64M x 256N.
__global__ __launch_bounds__(256) void k_gemm_A(const unsigned short* __restrict__ sh,
                                                const unsigned short* __restrict__ sl,
                                                const unsigned short* __restrict__ wh,
                                                const unsigned short* __restrict__ wl,
                                                unsigned short* __restrict__ A) {
    int tid = threadIdx.x, wid = tid >> 6, lane = tid & 63;
    int lr = lane & 15, kg = lane >> 4;
    int m0 = blockIdx.x * 64;
    int n0 = blockIdx.y * 256 + wid * 64;
    f32x4 acc[4][4] = {};
#pragma unroll
    for (int kb = 0; kb < 64; kb += 32) {
        bf16x8 ah[4], al[4], bh[4], bl[4];
#pragma unroll
        for (int mi = 0; mi < 4; ++mi) {
            size_t off = (size_t)(m0 + mi * 16 + lr) * 64 + kb + kg * 8;
            ah[mi] = *(const bf16x8*)(sh + off);
            al[mi] = *(const bf16x8*)(sl + off);
        }
#pragma unroll
        for (int ni = 0; ni < 4; ++ni) {
            size_t off = (size_t)(n0 + ni * 16 + lr) * 64 + kb + kg * 8;
            bh[ni] = *(const bf16x8*)(wh + off);
            bl[ni] = *(const bf16x8*)(wl + off);
        }
#pragma unroll
        for (int mi = 0; mi < 4; ++mi)
#pragma unroll
            for (int ni = 0; ni < 4; ++ni) {
                acc[mi][ni] = __builtin_amdgcn_mfma_f32_16x16x32_bf16(ah[mi], bh[ni], acc[mi][ni], 0, 0, 0);
                acc[mi][ni] = __builtin_amdgcn_mfma_f32_16x16x32_bf16(ah[mi], bl[ni], acc[mi][ni], 0, 0, 0);
                acc[mi][ni] = __builtin_amdgcn_mfma_f32_16x16x32_bf16(al[mi], bh[ni], acc[mi][ni], 0, 0, 0);
            }
    }
    // C/D layout (m89-verified): col = lane&15, row = (lane>>4)*4 + reg
#pragma unroll
    for (int mi = 0; mi < 4; ++mi)
#pragma unroll
        for (int r = 0; r < 4; ++r) {
            size_t row = (size_t)(m0 + mi * 16 + kg * 4 + r) * 2048;
#pragma unroll
            for (int ni = 0; ni < 4; ++ni)
                A[row + n0 + ni * 16 + lr] = f2bf(acc[mi][ni][r]);
        }
}

// ================================================================ CSR edge message + scatter
// wave per src node; A row pinned in 16 VGPRs across all out-edges.
__global__ __launch_bounds__(256) void k_edge(const int* __restrict__ ei,
                                              const int* __restrict__ start,
                                              const int* __restrict__ srccnt,
                                              const int* __restrict__ eord,
                                              const float* __restrict__ h32,
                                              const unsigned short* __restrict__ A,
                                              const float* __restrict__ cbuf,
                                              float* __restrict__ agg) {
    int tid = threadIdx.x, wid = tid >> 6, o = tid & 63;
    int n = blockIdx.x * 4 + wid;
    int cnt = srccnt[n];
    if (cnt == 0) return;
    int beg = start[n];
    float cv = cbuf[(size_t)n * DIM + o];
    const uint4* Ap = (const uint4*)(A + (size_t)n * 2048 + o * 32);
    uint4 a0 = Ap[0], a1 = Ap[1], a2 = Ap[2], a3 = Ap[3];
    for (int i = beg; i < beg + cnt; ++i) {
        int e = eord[i];
        int dst = ei[NE + e];
        const float4* hp = (const float4*)(h32 + (size_t)e * 32);
        float acc = cv;
        float4 hA = hp[0], hB = hp[1];
        acc += hA.x*bflo(a0.x) + hA.y*bfhi(a0.x) + hA.z*bflo(a0.y) + hA.w*bfhi(a0.y)
             + hB.x*bflo(a0.z) + hB.y*bfhi(a0.z) + hB.z*bflo(a0.w) + hB.w*bfhi(a0.w);
        hA = hp[2]; hB = hp[3];
        acc += hA.x*bflo(a1.x) + hA.y*bfhi(a1.x) + hA.z*bflo(a1.y) + hA.w*bfhi(a1.y)
             + hB.x*bflo(a1.z) + hB.y*bfhi(a1.z) + hB.z*bflo(a1.w) + hB.w*bfhi(a1.w);
        hA = hp[4]; hB = hp[5];
        acc += hA.x*bflo(a2.x) + hA.y*bfhi(a2.x) + hA.z*bflo(a2.y) + hA.w*bfhi(a2.y)
             + hB.x*bflo(a2.z) + hB.y*bfhi(a2.z) + hB.z*bflo(a2.w) + hB.w*bfhi(a2.w);
        hA = hp[6]; hB = hp[7];
        acc += hA.x*bflo(a3.x) + hA.y*bfhi(a3.x) + hA.z*bflo(a3.y) + hA.w*bfhi(a3.y)
             + hB.x*bflo(a3.z) + hB.y*bfhi(a3.z) + hB.z*bflo(a3.w) + hB.w*bfhi(a3.w);
        atomicAdd(&agg[(size_t)dst * DIM + o], acc);
    }
}

// ================================================================ NNConv combine + GRU cell (lean)
// 8 nodes/block (1024 blocks = 4/CU), 2 nodes/thread; float2-packed weights
// (3 loads/iter feed 12 FMAs). Self-zeroes agg. No epilogue (see k_post).
__global__ __launch_bounds__(256) void k_update(float* __restrict__ s,
                                                float* __restrict__ agg,
                                                const float* __restrict__ deg,
                                                const float* __restrict__ root,
                                                const float* __restrict__ conv_b,
                                                const float2* __restrict__ Wpk,
                                                const float* __restrict__ bih,
                                                const float* __restrict__ bhh) {
    __shared__ float sm_s[8][64];
    __shared__ float sm_m[8][64];
    int tid = threadIdx.x, w = tid >> 6, lane = tid & 63;
    int n0 = blockIdx.x * 8;
#pragma unroll
    for (int q = 0; q < 2; ++q) {
        int ln = w + q * 4;
        sm_s[ln][lane] = s[(size_t)(n0 + ln) * DIM + lane];
    }
    __syncthreads();
    float mval[2];
#pragma unroll
    for (int q = 0; q < 2; ++q) {
        int ln = w + q * 4, node = n0 + ln;
        size_t idx = (size_t)node * DIM + lane;
        mval[q] = agg[idx] / fmaxf(deg[node], 1.f) + conv_b[lane];
        agg[idx] = 0.f;                       // self-zero for next iteration
    }
    for (int i = 0; i < 64; ++i) {
        float rv = root[i * 64 + lane];
#pragma unroll
        for (int q = 0; q < 2; ++q) mval[q] += sm_s[w + q * 4][i] * rv;
    }
#pragma unroll
    for (int q = 0; q < 2; ++q) sm_m[w + q * 4][lane] = fmaxf(mval[q], 0.f);
    __syncthreads();
    float gr[2] = {}, gz[2] = {}, gn[2] = {}, hr[2] = {}, hz[2] = {}, hn[2] = {};
    for (int i = 0; i < 64; ++i) {
        float2 p0 = Wpk[i * 192 + lane];        // {Wih_r, Whh_r}
        float2 p1 = Wpk[i * 192 + 64 + lane];   // {Wih_z, Whh_z}
        float2 p2 = Wpk[i * 192 + 128 + lane];  // {Wih_n, Whh_n}
#pragma unroll
        for (int q = 0; q < 2; ++q) {
            int ln = w + q * 4;
            float mi = sm_m[ln][i], hi = sm_s[ln][i];
            gr[q] += mi * p0.x; hr[q] += hi * p0.y;
            gz[q] += mi * p1.x; hz[q] += hi * p1.y;
            gn[q] += mi * p2.x; hn[q] += hi * p2.y;
        }
    }
    float bi0 = bih[lane], bi1 = bih[64 + lane], bi2 = bih[128 + lane];
    float bh0 = bhh[lane], bh1 = bhh[64 + lane], bh2 = bhh[128 + lane];
#pragma unroll
    for (int q = 0; q < 2; ++q) {
        int ln = w + q * 4, node = n0 + ln;
        float r = 1.f / (1.f + expf(-(gr[q] + bi0 + hr[q] + bh0)));
        float z = 1.f / (1.f + expf(-(gz[q] + bi1 + hz[q] + bh1)));
        float nv = tanhf(gn[q] + bi2 + r * (hn[q] + bh2));
        float hv = sm_s[ln][lane];
        s[(size_t)node * DIM + lane] = (1.f - z) * nv + z * hv;
    }
}

// ================================================================ post-update: bf16 split + cbuf = h@b2
__global__ __launch_bounds__(256) void k_post(const float* __restrict__ s,
                                              unsigned short* __restrict__ shi,
                                              unsigned short* __restrict__ slo,
                                              float* __restrict__ cbuf,
                                              const float* __restrict__ b2) {
    __shared__ float sm[4][64];
    int tid = threadIdx.x, w = tid >> 6, lane = tid & 63;
    int node = blockIdx.x * 4 + w;
    size_t idx = (size_t)node * DIM + lane;
    float sv = s[idx];
    sm[w][lane] = sv;
    unsigned short hb = f2bf(sv);
    shi[idx] = hb; slo[idx] = f2bf(sv - ubf(hb));
    __syncthreads();
    float cv = 0.f;
    for (int i = 0; i < 64; ++i) cv += sm[w][i] * b2[i * 64 + lane];
    cbuf[idx] = cv;
}

// ================================================================ out_edges + out_combine
__global__ __launch_bounds__(256) void k_edges_out(const float* __restrict__ s,
                                                   const float* __restrict__ x,
                                                   const float* __restrict__ W1l,
                                                   const float* __restrict__ b1l,
                                                   const float* __restrict__ WUp,
                                                   const float* __restrict__ bUp,
                                                   float* __restrict__ oe,
                                                   float* __restrict__ oc) {
    __shared__ float sm_s[4][64];
    __shared__ float sm_oe[4][4];
    int tid = threadIdx.x, w = tid >> 6, lane = tid & 63;
    int node = blockIdx.x * 4 + w;
    float sv = s[(size_t)node * DIM + lane];
    sm_s[w][lane] = sv;
    __syncthreads();
    if (lane < 4) {
        float acc = b1l[lane];
        for (int i = 0; i < 64; ++i) acc += sm_s[w][i] * W1l[lane * 64 + i];
        acc = fmaxf(acc, 0.f);
        sm_oe[w][lane] = acc;
        oe[(size_t)node * 4 + lane] = acc;
    }
    __syncthreads();
    float ocv;
    if (x[(size_t)node * FD] == 2.0f) {
        ocv = bUp[lane];
#pragma unroll
        for (int t = 0; t < 4; ++t) ocv += sm_oe[w][t] * WUp[lane * 4 + t];
    } else {
        ocv = sv;
    }
    oc[(size_t)node * DIM + lane] = ocv;
}

// ================================================================ FGNet edge: me = oc[src] @ M[bond], scatter
__global__ __launch_bounds__(256) void k_fgedge(const int* __restrict__ ei,
                                                const int* __restrict__ bond,
                                                const float* __restrict__ oc,
                                                const float* __restrict__ M,
                                                float* __restrict__ fg_agg) {
    __shared__ float so[4][64];
    int tid = threadIdx.x, w = tid >> 6, lane = tid & 63;
    int e = blockIdx.x * 4 + w;
    int src = ei[e], dst = ei[NE + e];
    int b = bond[e];
    so[w][lane] = oc[(size_t)src * DIM + lane];
    __syncthreads();
    float acc = 0.f;
    const float* Mp = M + b * DIM * DIM;
    for (int d = 0; d < 64; ++d) acc += so[w][d] * Mp[d * 64 + lane];
    atomicAdd(&fg_agg[(size_t)dst * DIM + lane], acc);
}

// ================================================================ final: msg_f -> msg_to_edge -> out_edges -> log_softmax
__global__ __launch_bounds__(256) void k_final(const float* __restrict__ fg_agg,
                                               const float* __restrict__ deg,
                                               const float* __restrict__ oe,
                                               const float* __restrict__ WDown,
                                               const float* __restrict__ bDown,
                                               const float* __restrict__ weight_e,
                                               const float* __restrict__ linWe,
                                               const float* __restrict__ linbe,
                                               float* __restrict__ out) {
    int tid = threadIdx.x, w = tid >> 6, lane = tid & 63;
    int node = blockIdx.x * 4 + w;
    float degc = fmaxf(deg[node], 1.f);
    float mf = fmaxf(fg_agg[(size_t)node * DIM + lane] / degc, 0.f);
    float mte[4];
#pragma unroll
    for (int t = 0; t < 4; ++t) {
        float p = mf * WDown[t * 64 + lane];
#pragma unroll
        for (int off = 32; off; off >>= 1) p += __shfl_xor(p, off);
        mte[t] = p + bDown[t];
    }
    float val[4];
    float mx = -1e30f;
#pragma unroll
    for (int t = 0; t < 4; ++t) {
        float acc = linbe[t];
#pragma unroll
        for (int t2 = 0; t2 < 4; ++t2) acc += weight_e[t2] * mte[t2] * linWe[t * 4 + t2];
        val[t] = oe[(size_t)node * 4 + t] + fmaxf(acc, 0.f);
        mx = fmaxf(mx, val[t]);
    }
    float lse = 0.f;
#pragma unroll
    for (int t = 0; t < 4; ++t) lse += expf(val[t] - mx);
    lse = logf(lse);
    if (lane < 4) out[(size_t)node * 4 + lane] = val[lane] - mx - lse;
}

// ================================================================ host
extern "C" void kernel_launch(void* const* d_in, const int* in_sizes, int n_in,
                              void* d_out, int out_size, void* d_ws, size_t ws_size,
                              hipStream_t stream) {
    const float* x       = (const float*)d_in[0];
    const int*   ei      = (const int*)  d_in[1];
    const float* ea      = (const float*)d_in[2];
    const float* W0      = (const float*)d_in[3];
    const float* b0      = (const float*)d_in[4];
    const float* nnW1    = (const float*)d_in[5];
    const float* nnb1    = (const float*)d_in[6];
    const float* nnW2    = (const float*)d_in[7];
    const float* nnb2    = (const float*)d_in[8];
    const float* root    = (const float*)d_in[9];
    const float* conv_b  = (const float*)d_in[10];
    const float* Wih     = (const float*)d_in[11];
    const float* Whh     = (const float*)d_in[12];
    const float* bih     = (const float*)d_in[13];
    const float* bhh     = (const float*)d_in[14];
    const float* W1l     = (const float*)d_in[15];
    const float* b1l     = (const float*)d_in[16];
    const float* WUp     = (const float*)d_in[17];
    const float* bUp     = (const float*)d_in[18];
    const float* WDown   = (const float*)d_in[19];
    const float* bDown   = (const float*)d_in[20];
    const float* U       = (const float*)d_in[21];
    const float* V       = (const float*)d_in[22];
    // d_in[23..25] weight/linW/linb: dead code (node-'out' branch never reaches output)
    const float* weight_e= (const float*)d_in[26];
    const float* linWe   = (const float*)d_in[27];
    const float* linbe   = (const float*)d_in[28];
    float* out = (float*)d_out;

    char* ws = (char*)d_ws;
    size_t off = 0;
    auto alloc = [&](size_t bytes) { size_t o = off; off = (off + bytes + 255) & ~(size_t)255; return o; };
    // adjacency matters: deg+srccnt share one memset; agg+fg_agg share one memset
    float* deg    = (float*)(ws + alloc((size_t)NN * 4));            // 32KB
    int*   srccnt = (int*)  (ws + alloc((size_t)NN * 4));            // 32KB (adjacent)
    float* agg    = (float*)(ws + alloc((size_t)NN * DIM * 4));      // 2MB
    float* fg_agg = (float*)(ws + alloc((size_t)NN * DIM * 4));      // 2MB (adjacent)
    float* s      = (float*)(ws + alloc((size_t)NN * DIM * 4));
    unsigned short* shi = (unsigned short*)(ws + alloc((size_t)NN * DIM * 2));
    unsigned short* slo = (unsigned short*)(ws + alloc((size_t)NN * DIM * 2));
    float* cbuf   = (float*)(ws + alloc((size_t)NN * DIM * 4));
    float* h32    = (float*)(ws + alloc((size_t)NE * 32 * 4));
    int*   bond   = (int*)  (ws + alloc((size_t)NE * 4));
    int*   startp = (int*)  (ws + alloc((size_t)NN * 4));
    int*   cursor = (int*)  (ws + alloc((size_t)NN * 4));
    int*   eord   = (int*)  (ws + alloc((size_t)NE * 4));
    float* oe     = (float*)(ws + alloc((size_t)NN * 4 * 4));
    float* oc     = (float*)(ws + alloc((size_t)NN * DIM * 4));
    float* Mbuf   = (float*)(ws + alloc((size_t)BT * DIM * DIM * 4));
    float2* Wpk   = (float2*)(ws + alloc((size_t)64 * 192 * 8));
    unsigned short* w2h = (unsigned short*)(ws + alloc((size_t)2048 * 64 * 2));
    unsigned short* w2l = (unsigned short*)(ws + alloc((size_t)2048 * 64 * 2));
    unsigned short* Abuf = (unsigned short*)(ws + alloc((size_t)NN * 2048 * 2));
    (void)n_in; (void)in_sizes; (void)out_size; (void)ws_size;

    hipMemsetAsync(deg, 0, (size_t)2 * NN * 4, stream);              // deg + srccnt
    hipMemsetAsync(agg, 0, (size_t)2 * NN * DIM * 4, stream);        // agg + fg_agg

    k_prep0<<<6272, 256, 0, stream>>>(x, ei, ea, W0, b0, nnW1, nnb1, nnb2,
                                      s, shi, slo, cbuf, deg, srccnt, h32, bond);
    k_prep1<<<816, 256, 0, stream>>>(nnW2, Wih, Whh, U, V, w2h, w2l, Wpk, Mbuf);
    k_scan<<<1, 1024, 0, stream>>>(srccnt, startp, cursor);
    k_scatter<<<NE / 256, 256, 0, stream>>>(ei, cursor, eord);

    for (int it = 0; it < 3; ++it) {
        k_gemm_A<<<dim3(NN / 64, 2048 / 256), 256, 0, stream>>>(shi, slo, w2h, w2l, Abuf);
        k_edge<<<NN / 4, 256, 0, stream>>>(ei, startp, srccnt, eord, h32, Abuf, cbuf, agg);
        k_update<<<NN / 8, 256, 0, stream>>>(s, agg, deg, root, conv_b, Wpk, bih, bhh);
        if (it < 2)
            k_post<<<NN / 4, 256, 0, stream>>>(s, shi, slo, cbuf, nnb2);
    }

    k_edges_out<<<NN / 4, 256, 0, stream>>>(s, x, W1l, b1l, WUp, bUp, oe, oc);
    k_fgedge<<<NE / 4, 256, 0, stream>>>(ei, bond, oc, Mbuf, fg_agg);
    k_final<<<NN / 4, 256, 0, stream>>>(fg_agg, deg, oe, WDown, bDown, weight_e, linWe, linbe, out);
}

// Round 6
// 294.796 us; speedup vs baseline: 1.1960x; 1.0104x over previous
//
#include <hip/hip_runtime.h>
#include <hip/hip_bf16.h>

#define NN 8192      // nodes
#define NE 32768     // edges
#define FD 16        // features
#define DIM 64
#define BT 4
#define RANK 512

typedef __attribute__((ext_vector_type(8))) short bf16x8;
typedef __attribute__((ext_vector_type(4))) float f32x4;

__device__ inline unsigned short f2bf(float f) {
    union { float f; unsigned u; } c; c.f = f;
    return (unsigned short)((c.u + 0x7fffu + ((c.u >> 16) & 1u)) >> 16);
}
__device__ inline float ubf(unsigned short h) {
    union { unsigned u; float f; } c; c.u = ((unsigned)h) << 16; return c.f;
}
__device__ inline float bflo(unsigned u) { union { unsigned u; float f; } c; c.u = u << 16; return c.f; }
__device__ inline float bfhi(unsigned u) { union { unsigned u; float f; } c; c.u = u & 0xffff0000u; return c.f; }

// ================================================================ prep0:
//   [0,2048):    s = relu(x@W0.T+b0) + bf16 hi/lo split   (elementwise)
//   [2048,2176): degree histograms (dst float, src int)
//   [2176,6272): per-edge hidden h32 + bond argmax
__global__ __launch_bounds__(256) void k_prep0(
    const float* __restrict__ x, const int* __restrict__ ei, const float* __restrict__ ea,
    const float* __restrict__ W0, const float* __restrict__ b0,
    const float* __restrict__ nnW1, const float* __restrict__ nnb1,
    float* __restrict__ s, unsigned short* __restrict__ shi, unsigned short* __restrict__ slo,
    float* __restrict__ deg, int* __restrict__ srccnt,
    float* __restrict__ h32, int* __restrict__ bond)
{
    int bid = blockIdx.x, tid = threadIdx.x;
    if (bid < 2048) {
        int gid = bid * 256 + tid;          // gid = n*64 + d
        int n = gid >> 6, d = gid & 63;
        const float4* xr = (const float4*)(x + (size_t)n * FD);
        const float4* wr = (const float4*)(W0 + d * FD);
        float4 x0 = xr[0], x1 = xr[1], x2 = xr[2], x3 = xr[3];
        float4 w0 = wr[0], w1 = wr[1], w2 = wr[2], w3 = wr[3];
        float acc = b0[d]
            + x0.x*w0.x + x0.y*w0.y + x0.z*w0.z + x0.w*w0.w
            + x1.x*w1.x + x1.y*w1.y + x1.z*w1.z + x1.w*w1.w
            + x2.x*w2.x + x2.y*w2.y + x2.z*w2.z + x2.w*w2.w
            + x3.x*w3.x + x3.y*w3.y + x3.z*w3.z + x3.w*w3.w;
        float sv = fmaxf(acc, 0.f);
        s[gid] = sv;
        unsigned short h = f2bf(sv);
        shi[gid] = h; slo[gid] = f2bf(sv - ubf(h));
    } else if (bid < 2176) {
        int e = (bid - 2048) * 256 + tid;
        atomicAdd(&deg[ei[NE + e]], 1.0f);
        atomicAdd(&srccnt[ei[e]], 1);
    } else {
        int e = (bid - 2176) * 8 + (tid >> 5);
        int k = tid & 31;
        float a0 = ea[e * 4 + 0], a1 = ea[e * 4 + 1], a2 = ea[e * 4 + 2], a3 = ea[e * 4 + 3];
        float h = nnb1[k] + a0 * nnW1[k * 4 + 0] + a1 * nnW1[k * 4 + 1]
                          + a2 * nnW1[k * 4 + 2] + a3 * nnW1[k * 4 + 3];
        h32[e * 32 + k] = fmaxf(h, 0.f);
        if (k == 0) {
            int bi = 0; float bv = a0;
            if (a1 > bv) { bv = a1; bi = 1; }
            if (a2 > bv) { bv = a2; bi = 2; }
            if (a3 > bv) { bv = a3; bi = 3; }
            bond[e] = bi;
        }
    }
}

// ================================================================ prep1: weight conversions
//   [0,512):   W2T bf16 hi/lo (B-operand layout for A-GEMM)
//   [512,608): Wih/Whh bf16 hi/lo (already [col][k] row-major)
//   [608,624): rootT bf16 hi/lo  rt[o*64+i] = root[i*64+o]
//   [624,640): b2T  bf16 hi/lo  b2t[o*64+i] = b2[i*64+o]
//   [640,896): M[b] = V[b]@U[b]
__global__ __launch_bounds__(256) void k_prep1(
    const float* __restrict__ W2, const float* __restrict__ Wih, const float* __restrict__ Whh,
    const float* __restrict__ root, const float* __restrict__ b2,
    const float* __restrict__ U, const float* __restrict__ V,
    unsigned short* __restrict__ w2h, unsigned short* __restrict__ w2l,
    unsigned short* __restrict__ wihh, unsigned short* __restrict__ wihl,
    unsigned short* __restrict__ whhh, unsigned short* __restrict__ whhl,
    unsigned short* __restrict__ rth, unsigned short* __restrict__ rtl,
    unsigned short* __restrict__ b2th, unsigned short* __restrict__ b2tl,
    float* __restrict__ M)
{
    int bid = blockIdx.x, tid = threadIdx.x;
    if (bid < 512) {
        int gid = bid * 256 + tid;          // gid = col*64 + i
        int col = gid >> 6, i = gid & 63;
        float v = W2[(size_t)(i * 64 + (col >> 5)) * 32 + (col & 31)];
        unsigned short h = f2bf(v);
        w2h[gid] = h; w2l[gid] = f2bf(v - ubf(h));
    } else if (bid < 608) {
        int gid = (bid - 512) * 256 + tid;  // 24576 total
        if (gid < 12288) {
            float v = Wih[gid];
            unsigned short h = f2bf(v);
            wihh[gid] = h; wihl[gid] = f2bf(v - ubf(h));
        } else {
            int g = gid - 12288;
            float v = Whh[g];
            unsigned short h = f2bf(v);
            whhh[g] = h; whhl[g] = f2bf(v - ubf(h));
        }
    } else if (bid < 624) {
        int gid = (bid - 608) * 256 + tid;  // 4096: gid = o*64 + i
        int o = gid >> 6, i = gid & 63;
        float v = root[i * 64 + o];
        unsigned short h = f2bf(v);
        rth[gid] = h; rtl[gid] = f2bf(v - ubf(h));
    } else if (bid < 640) {
        int gid = (bid - 624) * 256 + tid;
        int o = gid >> 6, i = gid & 63;
        float v = b2[i * 64 + o];
        unsigned short h = f2bf(v);
        b2th[gid] = h; b2tl[gid] = f2bf(v - ubf(h));
    } else {
        __shared__ float red[4][64];
        int t = bid - 640;
        int b = t >> 6, d = t & 63;
        int chunk = tid >> 6, dp = tid & 63;
        const float* Vp = V + ((size_t)b * DIM + d) * RANK;
        const float* Up = U + (size_t)b * RANK * DIM;
        float acc = 0.f;
        for (int r = chunk * 128; r < chunk * 128 + 128; ++r)
            acc += Vp[r] * Up[(size_t)r * DIM + dp];
        red[chunk][dp] = acc;
        __syncthreads();
        if (chunk == 0)
            M[((size_t)b * DIM + d) * DIM + dp] =
                red[0][dp] + red[1][dp] + red[2][dp] + red[3][dp];
    }
}

// ================================================================ CSR: exclusive scan of src counts
__global__ __launch_bounds__(1024) void k_scan(const int* __restrict__ cnt,
                                               int* __restrict__ start, int* __restrict__ cursor) {
    __shared__ int ls[1024];
    int tid = threadIdx.x;
    int v[8], tot = 0;
#pragma unroll
    for (int j = 0; j < 8; ++j) { v[j] = cnt[tid * 8 + j]; tot += v[j]; }
    ls[tid] = tot;
    __syncthreads();
    for (int off = 1; off < 1024; off <<= 1) {
        int t = (tid >= off) ? ls[tid - off] : 0;
        __syncthreads();
        ls[tid] += t;
        __syncthreads();
    }
    int run = ls[tid] - tot;   // exclusive base
#pragma unroll
    for (int j = 0; j < 8; ++j) {
        start[tid * 8 + j] = run; cursor[tid * 8 + j] = run; run += v[j];
    }
}

__global__ __launch_bounds__(256) void k_scatter(const int* __restrict__ ei,
                                                 int* __restrict__ cursor, int* __restrict__ eord) {
    int e = blockIdx.x * 256 + threadIdx.x;
    int pos = atomicAdd(&cursor[ei[e]], 1);
    eord[pos] = e;
}

// ================================================================ A = s @ W2 (+ cbuf = s @ b2) via split-bf16 MFMA
// grid (128, 9): y<8 -> A bf16 out (4 waves x 64x64); y==8 -> cbuf fp32 out.
__global__ __launch_bounds__(256) void k_gemm_A(const unsigned short* __restrict__ sh,
                                                const unsigned short* __restrict__ sl,
                                                const unsigned short* __restrict__ wh,
                                                const unsigned short* __restrict__ wl,
                                                const unsigned short* __restrict__ b2th,
                                                const unsigned short* __restrict__ b2tl,
                                                unsigned short* __restrict__ A,
                                                float* __restrict__ cbuf) {
    int tid = threadIdx.x, wid = tid >> 6, lane = tid & 63;
    int lr = lane & 15, kg = lane >> 4;
    int m0 = blockIdx.x * 64;
    if (blockIdx.y == 8) {
        // cbuf: each wave one 16-row tile, N=64
        f32x4 acc[4] = {};
#pragma unroll
        for (int kb = 0; kb < 64; kb += 32) {
            size_t offA = (size_t)(m0 + wid * 16 + lr) * 64 + kb + kg * 8;
            bf16x8 ah = *(const bf16x8*)(sh + offA);
            bf16x8 al = *(const bf16x8*)(sl + offA);
#pragma unroll
            for (int ni = 0; ni < 4; ++ni) {
                size_t offB = (size_t)(ni * 16 + lr) * 64 + kb + kg * 8;
                bf16x8 bh = *(const bf16x8*)(b2th + offB);
                bf16x8 bl = *(const bf16x8*)(b2tl + offB);
                acc[ni] = __builtin_amdgcn_mfma_f32_16x16x32_bf16(ah, bh, acc[ni], 0, 0, 0);
                acc[ni] = __builtin_amdgcn_mfma_f32_16x16x32_bf16(ah, bl, acc[ni], 0, 0, 0);
                acc[ni] = __builtin_amdgcn_mfma_f32_16x16x32_bf16(al, bh, acc[ni], 0, 0, 0);
            }
        }
#pragma unroll
        for (int ni = 0; ni < 4; ++ni)
#pragma unroll
            for (int r = 0; r < 4; ++r)
                cbuf[(size_t)(m0 + wid * 16 + kg * 4 + r) * 64 + ni * 16 + lr] = acc[ni][r];
        return;
    }
    int n0 = blockIdx.y * 256 + wid * 64;
    f32x4 acc[4][4] = {};
#pragma unroll
    for (int kb = 0; kb < 64; kb += 32) {
        bf16x8 ah[4], al[4], bh[4], bl[4];
#pragma unroll
        for (int mi = 0; mi < 4; ++mi) {
            size_t off = (size_t)(m0 + mi * 16 + lr) * 64 + kb + kg * 8;
            ah[mi] = *(const bf16x8*)(sh + off);
            al[mi] = *(const bf16x8*)(sl + off);
        }
#pragma unroll
        for (int ni = 0; ni < 4; ++ni) {
            size_t off = (size_t)(n0 + ni * 16 + lr) * 64 + kb + kg * 8;
            bh[ni] = *(const bf16x8*)(wh + off);
            bl[ni] = *(const bf16x8*)(wl + off);
        }
#pragma unroll
        for (int mi = 0; mi < 4; ++mi)
#pragma unroll
            for (int ni = 0; ni < 4; ++ni) {
                acc[mi][ni] = __builtin_amdgcn_mfma_f32_16x16x32_bf16(ah[mi], bh[ni], acc[mi][ni], 0, 0, 0);
                acc[mi][ni] = __builtin_amdgcn_mfma_f32_16x16x32_bf16(ah[mi], bl[ni], acc[mi][ni], 0, 0, 0);
                acc[mi][ni] = __builtin_amdgcn_mfma_f32_16x16x32_bf16(al[mi], bh[ni], acc[mi][ni], 0, 0, 0);
            }
    }
#pragma unroll
    for (int mi = 0; mi < 4; ++mi)
#pragma unroll
        for (int r = 0; r < 4; ++r) {
            size_t row = (size_t)(m0 + mi * 16 + kg * 4 + r) * 2048;
#pragma unroll
            for (int ni = 0; ni < 4; ++ni)
                A[row + n0 + ni * 16 + lr] = f2bf(acc[mi][ni][r]);
        }
}

// ================================================================ CSR edge message + scatter
__global__ __launch_bounds__(256) void k_edge(const int* __restrict__ ei,
                                              const int* __restrict__ start,
                                              const int* __restrict__ srccnt,
                                              const int* __restrict__ eord,
                                              const float* __restrict__ h32,
                                              const unsigned short* __restrict__ A,
                                              const float* __restrict__ cbuf,
                                              float* __restrict__ agg) {
    int tid = threadIdx.x, wid = tid >> 6, o = tid & 63;
    int n = blockIdx.x * 4 + wid;
    int cnt = srccnt[n];
    if (cnt == 0) return;
    int beg = start[n];
    float cv = cbuf[(size_t)n * DIM + o];
    const uint4* Ap = (const uint4*)(A + (size_t)n * 2048 + o * 32);
    uint4 a0 = Ap[0], a1 = Ap[1], a2 = Ap[2], a3 = Ap[3];
    for (int i = beg; i < beg + cnt; ++i) {
        int e = eord[i];
        int dst = ei[NE + e];
        const float4* hp = (const float4*)(h32 + (size_t)e * 32);
        float acc = cv;
        float4 hA = hp[0], hB = hp[1];
        acc += hA.x*bflo(a0.x) + hA.y*bfhi(a0.x) + hA.z*bflo(a0.y) + hA.w*bfhi(a0.y)
             + hB.x*bflo(a0.z) + hB.y*bfhi(a0.z) + hB.z*bflo(a0.w) + hB.w*bfhi(a0.w);
        hA = hp[2]; hB = hp[3];
        acc += hA.x*bflo(a1.x) + hA.y*bfhi(a1.x) + hA.z*bflo(a1.y) + hA.w*bfhi(a1.y)
             + hB.x*bflo(a1.z) + hB.y*bfhi(a1.z) + hB.z*bflo(a1.w) + hB.w*bfhi(a1.w);
        hA = hp[4]; hB = hp[5];
        acc += hA.x*bflo(a2.x) + hA.y*bfhi(a2.x) + hA.z*bflo(a2.y) + hA.w*bfhi(a2.y)
             + hB.x*bflo(a2.z) + hB.y*bfhi(a2.z) + hB.z*bflo(a2.w) + hB.w*bfhi(a2.w);
        hA = hp[6]; hB = hp[7];
        acc += hA.x*bflo(a3.x) + hA.y*bfhi(a3.x) + hA.z*bflo(a3.y) + hA.w*bfhi(a3.y)
             + hB.x*bflo(a3.z) + hB.y*bfhi(a3.z) + hB.z*bflo(a3.w) + hB.w*bfhi(a3.w);
        atomicAdd(&agg[(size_t)dst * DIM + o], acc);
    }
}

// ================================================================ m = relu(s@root + agg/deg + conv_b), bf16 split; zero agg
// 512 blocks; each wave an independent 16-row x 64-col tile.
__global__ __launch_bounds__(256) void k_m(const unsigned short* __restrict__ sh,
                                           const unsigned short* __restrict__ sl,
                                           const unsigned short* __restrict__ rth,
                                           const unsigned short* __restrict__ rtl,
                                           float* __restrict__ agg,
                                           const float* __restrict__ deg,
                                           const float* __restrict__ conv_b,
                                           unsigned short* __restrict__ mhi,
                                           unsigned short* __restrict__ mlo) {
    int tid = threadIdx.x, wid = tid >> 6, lane = tid & 63;
    int lr = lane & 15, kg = lane >> 4;
    int m0 = (blockIdx.x * 4 + wid) * 16;
    f32x4 acc[4] = {};
#pragma unroll
    for (int kb = 0; kb < 64; kb += 32) {
        size_t offA = (size_t)(m0 + lr) * 64 + kb + kg * 8;
        bf16x8 ah = *(const bf16x8*)(sh + offA);
        bf16x8 al = *(const bf16x8*)(sl + offA);
#pragma unroll
        for (int ni = 0; ni < 4; ++ni) {
            size_t offB = (size_t)(ni * 16 + lr) * 64 + kb + kg * 8;
            bf16x8 bh = *(const bf16x8*)(rth + offB);
            bf16x8 bl = *(const bf16x8*)(rtl + offB);
            acc[ni] = __builtin_amdgcn_mfma_f32_16x16x32_bf16(ah, bh, acc[ni], 0, 0, 0);
            acc[ni] = __builtin_amdgcn_mfma_f32_16x16x32_bf16(ah, bl, acc[ni], 0, 0, 0);
            acc[ni] = __builtin_amdgcn_mfma_f32_16x16x32_bf16(al, bh, acc[ni], 0, 0, 0);
        }
    }
#pragma unroll
    for (int r = 0; r < 4; ++r) {
        int row = m0 + kg * 4 + r;
        float inv = 1.f / fmaxf(deg[row], 1.f);
#pragma unroll
        for (int ni = 0; ni < 4; ++ni) {
            int col = ni * 16 + lr;
            size_t idx = (size_t)row * 64 + col;
            float v = acc[ni][r] + agg[idx] * inv + conv_b[col];
            agg[idx] = 0.f;
            v = fmaxf(v, 0.f);
            unsigned short h = f2bf(v);
            mhi[idx] = h; mlo[idx] = f2bf(v - ubf(h));
        }
    }
}

// ================================================================ gates: gi = m@Wih.T (cols 0..191), gh = s@Whh.T (192..383)
// 256 blocks; wave = independent (16-row, 192-col) half-tile.
__global__ __launch_bounds__(256) void k_gates(const unsigned short* __restrict__ mhi,
                                               const unsigned short* __restrict__ mlo,
                                               const unsigned short* __restrict__ shi,
                                               const unsigned short* __restrict__ slo,
                                               const unsigned short* __restrict__ wihh,
                                               const unsigned short* __restrict__ wihl,
                                               const unsigned short* __restrict__ whhh,
                                               const unsigned short* __restrict__ whhl,
                                               float* __restrict__ gates) {
    int tid = threadIdx.x, wid = tid >> 6, lane = tid & 63;
    int lr = lane & 15, kg = lane >> 4;
    int tile = blockIdx.x * 4 + wid;     // 0..1023
    int mt = tile >> 1, half = tile & 1;
    int m0 = mt * 16;
    const unsigned short* Ah = half ? shi : mhi;
    const unsigned short* Al = half ? slo : mlo;
    const unsigned short* Bh = half ? whhh : wihh;
    const unsigned short* Bl = half ? whhl : wihl;
    f32x4 acc[12] = {};
#pragma unroll
    for (int kb = 0; kb < 64; kb += 32) {
        size_t offA = (size_t)(m0 + lr) * 64 + kb + kg * 8;
        bf16x8 ah = *(const bf16x8*)(Ah + offA);
        bf16x8 al = *(const bf16x8*)(Al + offA);
#pragma unroll
        for (int ni = 0; ni < 12; ++ni) {
            size_t offB = (size_t)(ni * 16 + lr) * 64 + kb + kg * 8;
            bf16x8 bh = *(const bf16x8*)(Bh + offB);
            bf16x8 bl = *(const bf16x8*)(Bl + offB);
            acc[ni] = __builtin_amdgcn_mfma_f32_16x16x32_bf16(ah, bh, acc[ni], 0, 0, 0);
            acc[ni] = __builtin_amdgcn_mfma_f32_16x16x32_bf16(ah, bl, acc[ni], 0, 0, 0);
            acc[ni] = __builtin_amdgcn_mfma_f32_16x16x32_bf16(al, bh, acc[ni], 0, 0, 0);
        }
    }
#pragma unroll
    for (int ni = 0; ni < 12; ++ni)
#pragma unroll
        for (int r = 0; r < 4; ++r)
            gates[(size_t)(m0 + kg * 4 + r) * 384 + half * 192 + ni * 16 + lr] = acc[ni][r];
}

// ================================================================ GRU elementwise: new s + bf16 split
__global__ __launch_bounds__(256) void k_gru(float* __restrict__ s,
                                             unsigned short* __restrict__ shi,
                                             unsigned short* __restrict__ slo,
                                             const float* __restrict__ gates,
                                             const float* __restrict__ bih,
                                             const float* __restrict__ bhh) {
    int gid = blockIdx.x * 256 + threadIdx.x;   // n*64 + d
    int n = gid >> 6, d = gid & 63;
    size_t base = (size_t)n * 384 + d;
    float ir = gates[base],       iz = gates[base + 64],  in_ = gates[base + 128];
    float hr = gates[base + 192], hz = gates[base + 256], hn = gates[base + 320];
    float hv = s[gid];
    float r = 1.f / (1.f + expf(-(ir + bih[d] + hr + bhh[d])));
    float z = 1.f / (1.f + expf(-(iz + bih[64 + d] + hz + bhh[64 + d])));
    float nv = tanhf(in_ + bih[128 + d] + r * (hn + bhh[128 + d]));
    float nh = (1.f - z) * nv + z * hv;
    s[gid] = nh;
    unsigned short h = f2bf(nh);
    shi[gid] = h; slo[gid] = f2bf(nh - ubf(h));
}

// ================================================================ out_edges + out_combine
__global__ __launch_bounds__(256) void k_edges_out(const float* __restrict__ s,
                                                   const float* __restrict__ x,
                                                   const float* __restrict__ W1l,
                                                   const float* __restrict__ b1l,
                                                   const float* __restrict__ WUp,
                                                   const float* __restrict__ bUp,
                                                   float* __restrict__ oe,
                                                   float* __restrict__ oc) {
    __shared__ float sm_s[4][64];
    __shared__ float sm_oe[4][4];
    int tid = threadIdx.x, w = tid >> 6, lane = tid & 63;
    int node = blockIdx.x * 4 + w;
    float sv = s[(size_t)node * DIM + lane];
    sm_s[w][lane] = sv;
    __syncthreads();
    if (lane < 4) {
        float acc = b1l[lane];
        for (int i = 0; i < 64; ++i) acc += sm_s[w][i] * W1l[lane * 64 + i];
        acc = fmaxf(acc, 0.f);
        sm_oe[w][lane] = acc;
        oe[(size_t)node * 4 + lane] = acc;
    }
    __syncthreads();
    float ocv;
    if (x[(size_t)node * FD] == 2.0f) {
        ocv = bUp[lane];
#pragma unroll
        for (int t = 0; t < 4; ++t) ocv += sm_oe[w][t] * WUp[lane * 4 + t];
    } else {
        ocv = sv;
    }
    oc[(size_t)node * DIM + lane] = ocv;
}

// ================================================================ FGNet edge: me = oc[src] @ M[bond], scatter
__global__ __launch_bounds__(256) void k_fgedge(const int* __restrict__ ei,
                                                const int* __restrict__ bond,
                                                const float* __restrict__ oc,
                                                const float* __restrict__ M,
                                                float* __restrict__ fg_agg) {
    __shared__ float so[4][64];
    int tid = threadIdx.x, w = tid >> 6, lane = tid & 63;
    int e = blockIdx.x * 4 + w;
    int src = ei[e], dst = ei[NE + e];
    int b = bond[e];
    so[w][lane] = oc[(size_t)src * DIM + lane];
    __syncthreads();
    float acc = 0.f;
    const float* Mp = M + b * DIM * DIM;
    for (int d = 0; d < 64; ++d) acc += so[w][d] * Mp[d * 64 + lane];
    atomicAdd(&fg_agg[(size_t)dst * DIM + lane], acc);
}

// ================================================================ final: msg_f -> msg_to_edge -> out_edges -> log_softmax
__global__ __launch_bounds__(256) void k_final(const float* __restrict__ fg_agg,
                                               const float* __restrict__ deg,
                                               const float* __restrict__ oe,
                                               const float* __restrict__ WDown,
                                               const float* __restrict__ bDown,
                                               const float* __restrict__ weight_e,
                                               const float* __restrict__ linWe,
                                               const float* __restrict__ linbe,
                                               float* __restrict__ out) {
    int tid = threadIdx.x, w = tid >> 6, lane = tid & 63;
    int node = blockIdx.x * 4 + w;
    float degc = fmaxf(deg[node], 1.f);
    float mf = fmaxf(fg_agg[(size_t)node * DIM + lane] / degc, 0.f);
    float mte[4];
#pragma unroll
    for (int t = 0; t < 4; ++t) {
        float p = mf * WDown[t * 64 + lane];
#pragma unroll
        for (int off = 32; off; off >>= 1) p += __shfl_xor(p, off);
        mte[t] = p + bDown[t];
    }
    float val[4];
    float mx = -1e30f;
#pragma unroll
    for (int t = 0; t < 4; ++t) {
        float acc = linbe[t];
#pragma unroll
        for (int t2 = 0; t2 < 4; ++t2) acc += weight_e[t2] * mte[t2] * linWe[t * 4 + t2];
        val[t] = oe[(size_t)node * 4 + t] + fmaxf(acc, 0.f);
        mx = fmaxf(mx, val[t]);
    }
    float lse = 0.f;
#pragma unroll
    for (int t = 0; t < 4; ++t) lse += expf(val[t] - mx);
    lse = logf(lse);
    if (lane < 4) out[(size_t)node * 4 + lane] = val[lane] - mx - lse;
}

// ================================================================ host
extern "C" void kernel_launch(void* const* d_in, const int* in_sizes, int n_in,
                              void* d_out, int out_size, void* d_ws, size_t ws_size,
                              hipStream_t stream) {
    const float* x       = (const float*)d_in[0];
    const int*   ei      = (const int*)  d_in[1];
    const float* ea      = (const float*)d_in[2];
    const float* W0      = (const float*)d_in[3];
    const float* b0      = (const float*)d_in[4];
    const float* nnW1    = (const float*)d_in[5];
    const float* nnb1    = (const float*)d_in[6];
    const float* nnW2    = (const float*)d_in[7];
    const float* nnb2    = (const float*)d_in[8];
    const float* root    = (const float*)d_in[9];
    const float* conv_b  = (const float*)d_in[10];
    const float* Wih     = (const float*)d_in[11];
    const float* Whh     = (const float*)d_in[12];
    const float* bih     = (const float*)d_in[13];
    const float* bhh     = (const float*)d_in[14];
    const float* W1l     = (const float*)d_in[15];
    const float* b1l     = (const float*)d_in[16];
    const float* WUp     = (const float*)d_in[17];
    const float* bUp     = (const float*)d_in[18];
    const float* WDown   = (const float*)d_in[19];
    const float* bDown   = (const float*)d_in[20];
    const float* U       = (const float*)d_in[21];
    const float* V       = (const float*)d_in[22];
    // d_in[23..25] weight/linW/linb: dead code (node-'out' branch never reaches output)
    const float* weight_e= (const float*)d_in[26];
    const float* linWe   = (const float*)d_in[27];
    const float* linbe   = (const float*)d_in[28];
    float* out = (float*)d_out;

    char* ws = (char*)d_ws;
    size_t off = 0;
    auto alloc = [&](size_t bytes) { size_t o = off; off = (off + bytes + 255) & ~(size_t)255; return o; };
    float* deg    = (float*)(ws + alloc((size_t)NN * 4));
    int*   srccnt = (int*)  (ws + alloc((size_t)NN * 4));            // adjacent to deg (one memset)
    float* agg    = (float*)(ws + alloc((size_t)NN * DIM * 4));
    float* fg_agg = (float*)(ws + alloc((size_t)NN * DIM * 4));      // adjacent to agg (one memset)
    float* s      = (float*)(ws + alloc((size_t)NN * DIM * 4));
    unsigned short* shi = (unsigned short*)(ws + alloc((size_t)NN * DIM * 2));
    unsigned short* slo = (unsigned short*)(ws + alloc((size_t)NN * DIM * 2));
    unsigned short* mhi = (unsigned short*)(ws + alloc((size_t)NN * DIM * 2));
    unsigned short* mlo = (unsigned short*)(ws + alloc((size_t)NN * DIM * 2));
    float* cbuf   = (float*)(ws + alloc((size_t)NN * DIM * 4));
    float* gates  = (float*)(ws + alloc((size_t)NN * 384 * 4));
    float* h32    = (float*)(ws + alloc((size_t)NE * 32 * 4));
    int*   bond   = (int*)  (ws + alloc((size_t)NE * 4));
    int*   startp = (int*)  (ws + alloc((size_t)NN * 4));
    int*   cursor = (int*)  (ws + alloc((size_t)NN * 4));
    int*   eord   = (int*)  (ws + alloc((size_t)NE * 4));
    float* oe     = (float*)(ws + alloc((size_t)NN * 4 * 4));
    float* oc     = (float*)(ws + alloc((size_t)NN * DIM * 4));
    float* Mbuf   = (float*)(ws + alloc((size_t)BT * DIM * DIM * 4));
    unsigned short* w2h = (unsigned short*)(ws + alloc((size_t)2048 * 64 * 2));
    unsigned short* w2l = (unsigned short*)(ws + alloc((size_t)2048 * 64 * 2));
    unsigned short* wihh = (unsigned short*)(ws + alloc((size_t)192 * 64 * 2));
    unsigned short* wihl = (unsigned short*)(ws + alloc((size_t)192 * 64 * 2));
    unsigned short* whhh = (unsigned short*)(ws + alloc((size_t)192 * 64 * 2));
    unsigned short* whhl = (unsigned short*)(ws + alloc((size_t)192 * 64 * 2));
    unsigned short* rth  = (unsigned short*)(ws + alloc((size_t)64 * 64 * 2));
    unsigned short* rtl  = (unsigned short*)(ws + alloc((size_t)64 * 64 * 2));
    unsigned short* b2th = (unsigned short*)(ws + alloc((size_t)64 * 64 * 2));
    unsigned short* b2tl = (unsigned short*)(ws + alloc((size_t)64 * 64 * 2));
    unsigned short* Abuf = (unsigned short*)(ws + alloc((size_t)NN * 2048 * 2));
    (void)n_in; (void)in_sizes; (void)out_size; (void)ws_size;

    hipMemsetAsync(deg, 0, (size_t)2 * NN * 4, stream);              // deg + srccnt
    hipMemsetAsync(agg, 0, (size_t)2 * NN * DIM * 4, stream);        // agg + fg_agg

    k_prep0<<<6272, 256, 0, stream>>>(x, ei, ea, W0, b0, nnW1, nnb1,
                                      s, shi, slo, deg, srccnt, h32, bond);
    k_prep1<<<896, 256, 0, stream>>>(nnW2, Wih, Whh, root, nnb2, U, V,
                                     w2h, w2l, wihh, wihl, whhh, whhl,
                                     rth, rtl, b2th, b2tl, Mbuf);
    k_scan<<<1, 1024, 0, stream>>>(srccnt, startp, cursor);
    k_scatter<<<NE / 256, 256, 0, stream>>>(ei, cursor, eord);

    for (int it = 0; it < 3; ++it) {
        k_gemm_A<<<dim3(NN / 64, 9), 256, 0, stream>>>(shi, slo, w2h, w2l, b2th, b2tl,
                                                       Abuf, cbuf);
        k_edge<<<NN / 4, 256, 0, stream>>>(ei, startp, srccnt, eord, h32, Abuf, cbuf, agg);
        k_m<<<NN / 16, 256, 0, stream>>>(shi, slo, rth, rtl, agg, deg, conv_b, mhi, mlo);
        k_gates<<<NN / 32, 256, 0, stream>>>(mhi, mlo, shi, slo,
                                             wihh, wihl, whhh, whhl, gates);
        k_gru<<<NN * DIM / 256, 256, 0, stream>>>(s, shi, slo, gates, bih, bhh);
    }

    k_edges_out<<<NN / 4, 256, 0, stream>>>(s, x, W1l, b1l, WUp, bUp, oe, oc);
    k_fgedge<<<NE / 4, 256, 0, stream>>>(ei, bond, oc, Mbuf, fg_agg);
    k_final<<<NN / 4, 256, 0, stream>>>(fg_agg, deg, oe, WDown, bDown, weight_e, linWe, linbe, out);
}

// Round 7
// 269.094 us; speedup vs baseline: 1.3103x; 1.0955x over previous
//
#include <hip/hip_runtime.h>
#include <hip/hip_bf16.h>

#define NN 8192      // nodes
#define NE 32768     // edges
#define FD 16        // features
#define DIM 64
#define BT 4
#define RANK 512

typedef __attribute__((ext_vector_type(8))) short bf16x8;
typedef __attribute__((ext_vector_type(4))) float f32x4;

__device__ inline unsigned short f2bf(float f) {
    union { float f; unsigned u; } c; c.f = f;
    return (unsigned short)((c.u + 0x7fffu + ((c.u >> 16) & 1u)) >> 16);
}
__device__ inline float ubf(unsigned short h) {
    union { unsigned u; float f; } c; c.u = ((unsigned)h) << 16; return c.f;
}
__device__ inline float bflo(unsigned u) { union { unsigned u; float f; } c; c.u = u << 16; return c.f; }
__device__ inline float bfhi(unsigned u) { union { unsigned u; float f; } c; c.u = u & 0xffff0000u; return c.f; }

// ================================================================ k_prep: all one-time prep fused
//   [0,2048):     s = relu(x@W0.T+b0) + bf16 hi/lo split
//   [2048,2176):  degree histograms (dst float, src int)
//   [2176,6272):  per-edge hidden h32 + bond argmax
//   [6272,6784):  W2T bf16 hi/lo (B-operand layout)
//   [6784,6880):  Wih/Whh bf16 hi/lo
//   [6880,6896):  rootT bf16 hi/lo
//   [6896,6912):  b2T bf16 hi/lo
//   [6912,7168):  M[b] = V[b]@U[b]
__global__ __launch_bounds__(256) void k_prep(
    const float* __restrict__ x, const int* __restrict__ ei, const float* __restrict__ ea,
    const float* __restrict__ W0, const float* __restrict__ b0,
    const float* __restrict__ nnW1, const float* __restrict__ nnb1,
    const float* __restrict__ W2, const float* __restrict__ Wih, const float* __restrict__ Whh,
    const float* __restrict__ root, const float* __restrict__ b2,
    const float* __restrict__ U, const float* __restrict__ V,
    float* __restrict__ s, unsigned short* __restrict__ shi, unsigned short* __restrict__ slo,
    float* __restrict__ deg, int* __restrict__ srccnt,
    float* __restrict__ h32, int* __restrict__ bond,
    unsigned short* __restrict__ w2h, unsigned short* __restrict__ w2l,
    unsigned short* __restrict__ wihh, unsigned short* __restrict__ wihl,
    unsigned short* __restrict__ whhh, unsigned short* __restrict__ whhl,
    unsigned short* __restrict__ rth, unsigned short* __restrict__ rtl,
    unsigned short* __restrict__ b2th, unsigned short* __restrict__ b2tl,
    float* __restrict__ M)
{
    int bid = blockIdx.x, tid = threadIdx.x;
    if (bid < 2048) {
        int gid = bid * 256 + tid;          // gid = n*64 + d
        int n = gid >> 6, d = gid & 63;
        const float4* xr = (const float4*)(x + (size_t)n * FD);
        const float4* wr = (const float4*)(W0 + d * FD);
        float4 x0 = xr[0], x1 = xr[1], x2 = xr[2], x3 = xr[3];
        float4 w0 = wr[0], w1 = wr[1], w2 = wr[2], w3 = wr[3];
        float acc = b0[d]
            + x0.x*w0.x + x0.y*w0.y + x0.z*w0.z + x0.w*w0.w
            + x1.x*w1.x + x1.y*w1.y + x1.z*w1.z + x1.w*w1.w
            + x2.x*w2.x + x2.y*w2.y + x2.z*w2.z + x2.w*w2.w
            + x3.x*w3.x + x3.y*w3.y + x3.z*w3.z + x3.w*w3.w;
        float sv = fmaxf(acc, 0.f);
        s[gid] = sv;
        unsigned short h = f2bf(sv);
        shi[gid] = h; slo[gid] = f2bf(sv - ubf(h));
    } else if (bid < 2176) {
        int e = (bid - 2048) * 256 + tid;
        atomicAdd(&deg[ei[NE + e]], 1.0f);
        atomicAdd(&srccnt[ei[e]], 1);
    } else if (bid < 6272) {
        int e = (bid - 2176) * 8 + (tid >> 5);
        int k = tid & 31;
        float a0 = ea[e * 4 + 0], a1 = ea[e * 4 + 1], a2 = ea[e * 4 + 2], a3 = ea[e * 4 + 3];
        float h = nnb1[k] + a0 * nnW1[k * 4 + 0] + a1 * nnW1[k * 4 + 1]
                          + a2 * nnW1[k * 4 + 2] + a3 * nnW1[k * 4 + 3];
        h32[e * 32 + k] = fmaxf(h, 0.f);
        if (k == 0) {
            int bi = 0; float bv = a0;
            if (a1 > bv) { bv = a1; bi = 1; }
            if (a2 > bv) { bv = a2; bi = 2; }
            if (a3 > bv) { bv = a3; bi = 3; }
            bond[e] = bi;
        }
    } else if (bid < 6784) {
        int gid = (bid - 6272) * 256 + tid;     // gid = col*64 + i
        int col = gid >> 6, i = gid & 63;
        float v = W2[(size_t)(i * 64 + (col >> 5)) * 32 + (col & 31)];
        unsigned short h = f2bf(v);
        w2h[gid] = h; w2l[gid] = f2bf(v - ubf(h));
    } else if (bid < 6880) {
        int gid = (bid - 6784) * 256 + tid;     // 24576 total
        if (gid < 12288) {
            float v = Wih[gid];
            unsigned short h = f2bf(v);
            wihh[gid] = h; wihl[gid] = f2bf(v - ubf(h));
        } else {
            int g = gid - 12288;
            float v = Whh[g];
            unsigned short h = f2bf(v);
            whhh[g] = h; whhl[g] = f2bf(v - ubf(h));
        }
    } else if (bid < 6896) {
        int gid = (bid - 6880) * 256 + tid;     // gid = o*64 + i
        int o = gid >> 6, i = gid & 63;
        float v = root[i * 64 + o];
        unsigned short h = f2bf(v);
        rth[gid] = h; rtl[gid] = f2bf(v - ubf(h));
    } else if (bid < 6912) {
        int gid = (bid - 6896) * 256 + tid;
        int o = gid >> 6, i = gid & 63;
        float v = b2[i * 64 + o];
        unsigned short h = f2bf(v);
        b2th[gid] = h; b2tl[gid] = f2bf(v - ubf(h));
    } else {
        __shared__ float red[4][64];
        int t = bid - 6912;
        int b = t >> 6, d = t & 63;
        int chunk = tid >> 6, dp = tid & 63;
        const float* Vp = V + ((size_t)b * DIM + d) * RANK;
        const float* Up = U + (size_t)b * RANK * DIM;
        float acc = 0.f;
        for (int r = chunk * 128; r < chunk * 128 + 128; ++r)
            acc += Vp[r] * Up[(size_t)r * DIM + dp];
        red[chunk][dp] = acc;
        __syncthreads();
        if (chunk == 0)
            M[((size_t)b * DIM + d) * DIM + dp] =
                red[0][dp] + red[1][dp] + red[2][dp] + red[3][dp];
    }
}

// ================================================================ CSR: exclusive scan of src counts
__global__ __launch_bounds__(1024) void k_scan(const int* __restrict__ cnt,
                                               int* __restrict__ start, int* __restrict__ cursor) {
    __shared__ int ls[1024];
    int tid = threadIdx.x;
    int v[8], tot = 0;
#pragma unroll
    for (int j = 0; j < 8; ++j) { v[j] = cnt[tid * 8 + j]; tot += v[j]; }
    ls[tid] = tot;
    __syncthreads();
    for (int off = 1; off < 1024; off <<= 1) {
        int t = (tid >= off) ? ls[tid - off] : 0;
        __syncthreads();
        ls[tid] += t;
        __syncthreads();
    }
    int run = ls[tid] - tot;   // exclusive base
#pragma unroll
    for (int j = 0; j < 8; ++j) {
        start[tid * 8 + j] = run; cursor[tid * 8 + j] = run; run += v[j];
    }
}

__global__ __launch_bounds__(256) void k_scatter(const int* __restrict__ ei,
                                                 int* __restrict__ cursor, int* __restrict__ eord) {
    int e = blockIdx.x * 256 + threadIdx.x;
    int pos = atomicAdd(&cursor[ei[e]], 1);
    eord[pos] = e;
}

// ================================================================ A = s @ W2 (+ cbuf = s @ b2) via split-bf16 MFMA
// grid (128, 9): y<8 -> A bf16 out (4 waves x 64x64); y==8 -> cbuf fp32 out.
__global__ __launch_bounds__(256) void k_gemm_A(const unsigned short* __restrict__ sh,
                                                const unsigned short* __restrict__ sl,
                                                const unsigned short* __restrict__ wh,
                                                const unsigned short* __restrict__ wl,
                                                const unsigned short* __restrict__ b2th,
                                                const unsigned short* __restrict__ b2tl,
                                                unsigned short* __restrict__ A,
                                                float* __restrict__ cbuf) {
    int tid = threadIdx.x, wid = tid >> 6, lane = tid & 63;
    int lr = lane & 15, kg = lane >> 4;
    int m0 = blockIdx.x * 64;
    if (blockIdx.y == 8) {
        f32x4 acc[4] = {};
#pragma unroll
        for (int kb = 0; kb < 64; kb += 32) {
            size_t offA = (size_t)(m0 + wid * 16 + lr) * 64 + kb + kg * 8;
            bf16x8 ah = *(const bf16x8*)(sh + offA);
            bf16x8 al = *(const bf16x8*)(sl + offA);
#pragma unroll
            for (int ni = 0; ni < 4; ++ni) {
                size_t offB = (size_t)(ni * 16 + lr) * 64 + kb + kg * 8;
                bf16x8 bh = *(const bf16x8*)(b2th + offB);
                bf16x8 bl = *(const bf16x8*)(b2tl + offB);
                acc[ni] = __builtin_amdgcn_mfma_f32_16x16x32_bf16(ah, bh, acc[ni], 0, 0, 0);
                acc[ni] = __builtin_amdgcn_mfma_f32_16x16x32_bf16(ah, bl, acc[ni], 0, 0, 0);
                acc[ni] = __builtin_amdgcn_mfma_f32_16x16x32_bf16(al, bh, acc[ni], 0, 0, 0);
            }
        }
#pragma unroll
        for (int ni = 0; ni < 4; ++ni)
#pragma unroll
            for (int r = 0; r < 4; ++r)
                cbuf[(size_t)(m0 + wid * 16 + kg * 4 + r) * 64 + ni * 16 + lr] = acc[ni][r];
        return;
    }
    int n0 = blockIdx.y * 256 + wid * 64;
    f32x4 acc[4][4] = {};
#pragma unroll
    for (int kb = 0; kb < 64; kb += 32) {
        bf16x8 ah[4], al[4], bh[4], bl[4];
#pragma unroll
        for (int mi = 0; mi < 4; ++mi) {
            size_t off = (size_t)(m0 + mi * 16 + lr) * 64 + kb + kg * 8;
            ah[mi] = *(const bf16x8*)(sh + off);
            al[mi] = *(const bf16x8*)(sl + off);
        }
#pragma unroll
        for (int ni = 0; ni < 4; ++ni) {
            size_t off = (size_t)(n0 + ni * 16 + lr) * 64 + kb + kg * 8;
            bh[ni] = *(const bf16x8*)(wh + off);
            bl[ni] = *(const bf16x8*)(wl + off);
        }
#pragma unroll
        for (int mi = 0; mi < 4; ++mi)
#pragma unroll
            for (int ni = 0; ni < 4; ++ni) {
                acc[mi][ni] = __builtin_amdgcn_mfma_f32_16x16x32_bf16(ah[mi], bh[ni], acc[mi][ni], 0, 0, 0);
                acc[mi][ni] = __builtin_amdgcn_mfma_f32_16x16x32_bf16(ah[mi], bl[ni], acc[mi][ni], 0, 0, 0);
                acc[mi][ni] = __builtin_amdgcn_mfma_f32_16x16x32_bf16(al[mi], bh[ni], acc[mi][ni], 0, 0, 0);
            }
    }
#pragma unroll
    for (int mi = 0; mi < 4; ++mi)
#pragma unroll
        for (int r = 0; r < 4; ++r) {
            size_t row = (size_t)(m0 + mi * 16 + kg * 4 + r) * 2048;
#pragma unroll
            for (int ni = 0; ni < 4; ++ni)
                A[row + n0 + ni * 16 + lr] = f2bf(acc[mi][ni][r]);
        }
}

// ================================================================ CSR edge message + scatter
__global__ __launch_bounds__(256) void k_edge(const int* __restrict__ ei,
                                              const int* __restrict__ start,
                                              const int* __restrict__ srccnt,
                                              const int* __restrict__ eord,
                                              const float* __restrict__ h32,
                                              const unsigned short* __restrict__ A,
                                              const float* __restrict__ cbuf,
                                              float* __restrict__ agg) {
    int tid = threadIdx.x, wid = tid >> 6, o = tid & 63;
    int n = blockIdx.x * 4 + wid;
    int cnt = srccnt[n];
    if (cnt == 0) return;
    int beg = start[n];
    float cv = cbuf[(size_t)n * DIM + o];
    const uint4* Ap = (const uint4*)(A + (size_t)n * 2048 + o * 32);
    uint4 a0 = Ap[0], a1 = Ap[1], a2 = Ap[2], a3 = Ap[3];
    for (int i = beg; i < beg + cnt; ++i) {
        int e = eord[i];
        int dst = ei[NE + e];
        const float4* hp = (const float4*)(h32 + (size_t)e * 32);
        float acc = cv;
        float4 hA = hp[0], hB = hp[1];
        acc += hA.x*bflo(a0.x) + hA.y*bfhi(a0.x) + hA.z*bflo(a0.y) + hA.w*bfhi(a0.y)
             + hB.x*bflo(a0.z) + hB.y*bfhi(a0.z) + hB.z*bflo(a0.w) + hB.w*bfhi(a0.w);
        hA = hp[2]; hB = hp[3];
        acc += hA.x*bflo(a1.x) + hA.y*bfhi(a1.x) + hA.z*bflo(a1.y) + hA.w*bfhi(a1.y)
             + hB.x*bflo(a1.z) + hB.y*bfhi(a1.z) + hB.z*bflo(a1.w) + hB.w*bfhi(a1.w);
        hA = hp[4]; hB = hp[5];
        acc += hA.x*bflo(a2.x) + hA.y*bfhi(a2.x) + hA.z*bflo(a2.y) + hA.w*bfhi(a2.y)
             + hB.x*bflo(a2.z) + hB.y*bfhi(a2.z) + hB.z*bflo(a2.w) + hB.w*bfhi(a2.w);
        hA = hp[6]; hB = hp[7];
        acc += hA.x*bflo(a3.x) + hA.y*bfhi(a3.x) + hA.z*bflo(a3.y) + hA.w*bfhi(a3.y)
             + hB.x*bflo(a3.z) + hB.y*bfhi(a3.z) + hB.z*bflo(a3.w) + hB.w*bfhi(a3.w);
        atomicAdd(&agg[(size_t)dst * DIM + o], acc);
    }
}

// ================================================================ fused update: m -> gates -> GRU, one wave per 16-row tile
// m = relu(s@rootT + agg/deg + conv_b)  (MFMA, then hi/lo split via LDS)
// gi = m@Wih.T, gh = s@Whh.T            (MFMA, 24 accs in-register)
// GRU fully in-lane: cols d, d+64, d+128 are all == lr (mod 16).
__global__ __launch_bounds__(64) void k_upd(
    float* __restrict__ s, unsigned short* __restrict__ shi, unsigned short* __restrict__ slo,
    float* __restrict__ agg, const float* __restrict__ deg, const float* __restrict__ conv_b,
    const unsigned short* __restrict__ rth, const unsigned short* __restrict__ rtl,
    const unsigned short* __restrict__ wihh, const unsigned short* __restrict__ wihl,
    const unsigned short* __restrict__ whhh, const unsigned short* __restrict__ whhl,
    const float* __restrict__ bih, const float* __restrict__ bhh)
{
    __shared__ unsigned short mh_l[16 * 64];
    __shared__ unsigned short ml_l[16 * 64];
    int lane = threadIdx.x;
    int lr = lane & 15, kg = lane >> 4;
    int m0 = blockIdx.x * 16;

    // s A-fragments (16 rows x K=64)
    bf16x8 sa_h[2], sa_l[2];
#pragma unroll
    for (int kb = 0; kb < 2; ++kb) {
        size_t off = (size_t)(m0 + lr) * 64 + kb * 32 + kg * 8;
        sa_h[kb] = *(const bf16x8*)(shi + off);
        sa_l[kb] = *(const bf16x8*)(slo + off);
    }
    // m = s @ rootT
    f32x4 macc[4] = {};
#pragma unroll
    for (int kb = 0; kb < 2; ++kb)
#pragma unroll
        for (int ni = 0; ni < 4; ++ni) {
            size_t offB = (size_t)(ni * 16 + lr) * 64 + kb * 32 + kg * 8;
            bf16x8 bh = *(const bf16x8*)(rth + offB);
            bf16x8 bl = *(const bf16x8*)(rtl + offB);
            macc[ni] = __builtin_amdgcn_mfma_f32_16x16x32_bf16(sa_h[kb], bh, macc[ni], 0, 0, 0);
            macc[ni] = __builtin_amdgcn_mfma_f32_16x16x32_bf16(sa_h[kb], bl, macc[ni], 0, 0, 0);
            macc[ni] = __builtin_amdgcn_mfma_f32_16x16x32_bf16(sa_l[kb], bh, macc[ni], 0, 0, 0);
        }
    // epilogue: +agg/deg + conv_b, relu, hi/lo split into LDS
#pragma unroll
    for (int r = 0; r < 4; ++r) {
        int row = m0 + kg * 4 + r;
        float inv = 1.f / fmaxf(deg[row], 1.f);
#pragma unroll
        for (int ni = 0; ni < 4; ++ni) {
            int col = ni * 16 + lr;
            size_t idx = (size_t)row * 64 + col;
            float v = macc[ni][r] + agg[idx] * inv + conv_b[col];
            agg[idx] = 0.f;                       // self-zero for next iteration
            v = fmaxf(v, 0.f);
            unsigned short h = f2bf(v);
            int loff = (kg * 4 + r) * 64 + col;
            mh_l[loff] = h; ml_l[loff] = f2bf(v - ubf(h));
        }
    }
    __syncthreads();
    // m A-fragments from LDS
    bf16x8 ma_h[2], ma_l[2];
#pragma unroll
    for (int kb = 0; kb < 2; ++kb) {
        int loff = lr * 64 + kb * 32 + kg * 8;
        ma_h[kb] = *(const bf16x8*)(mh_l + loff);
        ma_l[kb] = *(const bf16x8*)(ml_l + loff);
    }
    // gi = m @ Wih.T  (12 accs), gh = s @ Whh.T (12 accs)
    f32x4 gacc[12] = {}, hacc[12] = {};
#pragma unroll
    for (int kb = 0; kb < 2; ++kb)
#pragma unroll
        for (int ni = 0; ni < 12; ++ni) {
            size_t offB = (size_t)(ni * 16 + lr) * 64 + kb * 32 + kg * 8;
            bf16x8 bh = *(const bf16x8*)(wihh + offB);
            bf16x8 bl = *(const bf16x8*)(wihl + offB);
            gacc[ni] = __builtin_amdgcn_mfma_f32_16x16x32_bf16(ma_h[kb], bh, gacc[ni], 0, 0, 0);
            gacc[ni] = __builtin_amdgcn_mfma_f32_16x16x32_bf16(ma_h[kb], bl, gacc[ni], 0, 0, 0);
            gacc[ni] = __builtin_amdgcn_mfma_f32_16x16x32_bf16(ma_l[kb], bh, gacc[ni], 0, 0, 0);
            bf16x8 ch = *(const bf16x8*)(whhh + offB);
            bf16x8 cl = *(const bf16x8*)(whhl + offB);
            hacc[ni] = __builtin_amdgcn_mfma_f32_16x16x32_bf16(sa_h[kb], ch, hacc[ni], 0, 0, 0);
            hacc[ni] = __builtin_amdgcn_mfma_f32_16x16x32_bf16(sa_h[kb], cl, hacc[ni], 0, 0, 0);
            hacc[ni] = __builtin_amdgcn_mfma_f32_16x16x32_bf16(sa_l[kb], ch, hacc[ni], 0, 0, 0);
        }
    // GRU in-register: lane (lr,kg) owns rows kg*4+r, cols lr+16j
#pragma unroll
    for (int j = 0; j < 4; ++j) {
        int d = lr + 16 * j;
        float bi0 = bih[d], bi1 = bih[64 + d], bi2 = bih[128 + d];
        float bh0 = bhh[d], bh1 = bhh[64 + d], bh2 = bhh[128 + d];
#pragma unroll
        for (int r = 0; r < 4; ++r) {
            int row = m0 + kg * 4 + r;
            size_t idx = (size_t)row * 64 + d;
            float ir = gacc[j][r], iz = gacc[4 + j][r], in_ = gacc[8 + j][r];
            float hr_ = hacc[j][r], hz = hacc[4 + j][r], hn = hacc[8 + j][r];
            float hv = s[idx];
            float rg = 1.f / (1.f + expf(-(ir + bi0 + hr_ + bh0)));
            float z  = 1.f / (1.f + expf(-(iz + bi1 + hz + bh1)));
            float nv = tanhf(in_ + bi2 + rg * (hn + bh2));
            float nh = (1.f - z) * nv + z * hv;
            s[idx] = nh;
            unsigned short hb = f2bf(nh);
            shi[idx] = hb; slo[idx] = f2bf(nh - ubf(hb));
        }
    }
}

// ================================================================ out_edges + out_combine
__global__ __launch_bounds__(256) void k_edges_out(const float* __restrict__ s,
                                                   const float* __restrict__ x,
                                                   const float* __restrict__ W1l,
                                                   const float* __restrict__ b1l,
                                                   const float* __restrict__ WUp,
                                                   const float* __restrict__ bUp,
                                                   float* __restrict__ oe,
                                                   float* __restrict__ oc) {
    __shared__ float sm_s[4][64];
    __shared__ float sm_oe[4][4];
    int tid = threadIdx.x, w = tid >> 6, lane = tid & 63;
    int node = blockIdx.x * 4 + w;
    float sv = s[(size_t)node * DIM + lane];
    sm_s[w][lane] = sv;
    __syncthreads();
    if (lane < 4) {
        float acc = b1l[lane];
        for (int i = 0; i < 64; ++i) acc += sm_s[w][i] * W1l[lane * 64 + i];
        acc = fmaxf(acc, 0.f);
        sm_oe[w][lane] = acc;
        oe[(size_t)node * 4 + lane] = acc;
    }
    __syncthreads();
    float ocv;
    if (x[(size_t)node * FD] == 2.0f) {
        ocv = bUp[lane];
#pragma unroll
        for (int t = 0; t < 4; ++t) ocv += sm_oe[w][t] * WUp[lane * 4 + t];
    } else {
        ocv = sv;
    }
    oc[(size_t)node * DIM + lane] = ocv;
}

// ================================================================ FGNet edge: me = oc[src] @ M[bond], scatter
__global__ __launch_bounds__(256) void k_fgedge(const int* __restrict__ ei,
                                                const int* __restrict__ bond,
                                                const float* __restrict__ oc,
                                                const float* __restrict__ M,
                                                float* __restrict__ fg_agg) {
    __shared__ float so[4][64];
    int tid = threadIdx.x, w = tid >> 6, lane = tid & 63;
    int e = blockIdx.x * 4 + w;
    int src = ei[e], dst = ei[NE + e];
    int b = bond[e];
    so[w][lane] = oc[(size_t)src * DIM + lane];
    __syncthreads();
    float acc = 0.f;
    const float* Mp = M + b * DIM * DIM;
    for (int d = 0; d < 64; ++d) acc += so[w][d] * Mp[d * 64 + lane];
    atomicAdd(&fg_agg[(size_t)dst * DIM + lane], acc);
}

// ================================================================ final: msg_f -> msg_to_edge -> out_edges -> log_softmax
__global__ __launch_bounds__(256) void k_final(const float* __restrict__ fg_agg,
                                               const float* __restrict__ deg,
                                               const float* __restrict__ oe,
                                               const float* __restrict__ WDown,
                                               const float* __restrict__ bDown,
                                               const float* __restrict__ weight_e,
                                               const float* __restrict__ linWe,
                                               const float* __restrict__ linbe,
                                               float* __restrict__ out) {
    int tid = threadIdx.x, w = tid >> 6, lane = tid & 63;
    int node = blockIdx.x * 4 + w;
    float degc = fmaxf(deg[node], 1.f);
    float mf = fmaxf(fg_agg[(size_t)node * DIM + lane] / degc, 0.f);
    float mte[4];
#pragma unroll
    for (int t = 0; t < 4; ++t) {
        float p = mf * WDown[t * 64 + lane];
#pragma unroll
        for (int off = 32; off; off >>= 1) p += __shfl_xor(p, off);
        mte[t] = p + bDown[t];
    }
    float val[4];
    float mx = -1e30f;
#pragma unroll
    for (int t = 0; t < 4; ++t) {
        float acc = linbe[t];
#pragma unroll
        for (int t2 = 0; t2 < 4; ++t2) acc += weight_e[t2] * mte[t2] * linWe[t * 4 + t2];
        val[t] = oe[(size_t)node * 4 + t] + fmaxf(acc, 0.f);
        mx = fmaxf(mx, val[t]);
    }
    float lse = 0.f;
#pragma unroll
    for (int t = 0; t < 4; ++t) lse += expf(val[t] - mx);
    lse = logf(lse);
    if (lane < 4) out[(size_t)node * 4 + lane] = val[lane] - mx - lse;
}

// ================================================================ host
extern "C" void kernel_launch(void* const* d_in, const int* in_sizes, int n_in,
                              void* d_out, int out_size, void* d_ws, size_t ws_size,
                              hipStream_t stream) {
    const float* x       = (const float*)d_in[0];
    const int*   ei      = (const int*)  d_in[1];
    const float* ea      = (const float*)d_in[2];
    const float* W0      = (const float*)d_in[3];
    const float* b0      = (const float*)d_in[4];
    const float* nnW1    = (const float*)d_in[5];
    const float* nnb1    = (const float*)d_in[6];
    const float* nnW2    = (const float*)d_in[7];
    const float* nnb2    = (const float*)d_in[8];
    const float* root    = (const float*)d_in[9];
    const float* conv_b  = (const float*)d_in[10];
    const float* Wih     = (const float*)d_in[11];
    const float* Whh     = (const float*)d_in[12];
    const float* bih     = (const float*)d_in[13];
    const float* bhh     = (const float*)d_in[14];
    const float* W1l     = (const float*)d_in[15];
    const float* b1l     = (const float*)d_in[16];
    const float* WUp     = (const float*)d_in[17];
    const float* bUp     = (const float*)d_in[18];
    const float* WDown   = (const float*)d_in[19];
    const float* bDown   = (const float*)d_in[20];
    const float* U       = (const float*)d_in[21];
    const float* V       = (const float*)d_in[22];
    // d_in[23..25] weight/linW/linb: dead code (node-'out' branch never reaches output)
    const float* weight_e= (const float*)d_in[26];
    const float* linWe   = (const float*)d_in[27];
    const float* linbe   = (const float*)d_in[28];
    float* out = (float*)d_out;

    char* ws = (char*)d_ws;
    size_t off = 0;
    auto alloc = [&](size_t bytes) { size_t o = off; off = (off + bytes + 255) & ~(size_t)255; return o; };
    float* deg    = (float*)(ws + alloc((size_t)NN * 4));
    int*   srccnt = (int*)  (ws + alloc((size_t)NN * 4));            // adjacent to deg (one memset)
    float* agg    = (float*)(ws + alloc((size_t)NN * DIM * 4));
    float* fg_agg = (float*)(ws + alloc((size_t)NN * DIM * 4));      // adjacent to agg (one memset)
    float* s      = (float*)(ws + alloc((size_t)NN * DIM * 4));
    unsigned short* shi = (unsigned short*)(ws + alloc((size_t)NN * DIM * 2));
    unsigned short* slo = (unsigned short*)(ws + alloc((size_t)NN * DIM * 2));
    float* cbuf   = (float*)(ws + alloc((size_t)NN * DIM * 4));
    float* h32    = (float*)(ws + alloc((size_t)NE * 32 * 4));
    int*   bond   = (int*)  (ws + alloc((size_t)NE * 4));
    int*   startp = (int*)  (ws + alloc((size_t)NN * 4));
    int*   cursor = (int*)  (ws + alloc((size_t)NN * 4));
    int*   eord   = (int*)  (ws + alloc((size_t)NE * 4));
    float* oe     = (float*)(ws + alloc((size_t)NN * 4 * 4));
    float* oc     = (float*)(ws + alloc((size_t)NN * DIM * 4));
    float* Mbuf   = (float*)(ws + alloc((size_t)BT * DIM * DIM * 4));
    unsigned short* w2h = (unsigned short*)(ws + alloc((size_t)2048 * 64 * 2));
    unsigned short* w2l = (unsigned short*)(ws + alloc((size_t)2048 * 64 * 2));
    unsigned short* wihh = (unsigned short*)(ws + alloc((size_t)192 * 64 * 2));
    unsigned short* wihl = (unsigned short*)(ws + alloc((size_t)192 * 64 * 2));
    unsigned short* whhh = (unsigned short*)(ws + alloc((size_t)192 * 64 * 2));
    unsigned short* whhl = (unsigned short*)(ws + alloc((size_t)192 * 64 * 2));
    unsigned short* rth  = (unsigned short*)(ws + alloc((size_t)64 * 64 * 2));
    unsigned short* rtl  = (unsigned short*)(ws + alloc((size_t)64 * 64 * 2));
    unsigned short* b2th = (unsigned short*)(ws + alloc((size_t)64 * 64 * 2));
    unsigned short* b2tl = (unsigned short*)(ws + alloc((size_t)64 * 64 * 2));
    unsigned short* Abuf = (unsigned short*)(ws + alloc((size_t)NN * 2048 * 2));
    (void)n_in; (void)in_sizes; (void)out_size; (void)ws_size;

    hipMemsetAsync(deg, 0, (size_t)2 * NN * 4, stream);              // deg + srccnt
    hipMemsetAsync(agg, 0, (size_t)2 * NN * DIM * 4, stream);        // agg + fg_agg

    k_prep<<<7168, 256, 0, stream>>>(x, ei, ea, W0, b0, nnW1, nnb1,
                                     nnW2, Wih, Whh, root, nnb2, U, V,
                                     s, shi, slo, deg, srccnt, h32, bond,
                                     w2h, w2l, wihh, wihl, whhh, whhl,
                                     rth, rtl, b2th, b2tl, Mbuf);
    k_scan<<<1, 1024, 0, stream>>>(srccnt, startp, cursor);
    k_scatter<<<NE / 256, 256, 0, stream>>>(ei, cursor, eord);

    for (int it = 0; it < 3; ++it) {
        k_gemm_A<<<dim3(NN / 64, 9), 256, 0, stream>>>(shi, slo, w2h, w2l, b2th, b2tl,
                                                       Abuf, cbuf);
        k_edge<<<NN / 4, 256, 0, stream>>>(ei, startp, srccnt, eord, h32, Abuf, cbuf, agg);
        k_upd<<<NN / 16, 64, 0, stream>>>(s, shi, slo, agg, deg, conv_b,
                                          rth, rtl, wihh, wihl, whhh, whhl, bih, bhh);
    }

    k_edges_out<<<NN / 4, 256, 0, stream>>>(s, x, W1l, b1l, WUp, bUp, oe, oc);
    k_fgedge<<<NE / 4, 256, 0, stream>>>(ei, bond, oc, Mbuf, fg_agg);
    k_final<<<NN / 4, 256, 0, stream>>>(fg_agg, deg, oe, WDown, bDown, weight_e, linWe, linbe, out);
}

// Round 8
// 242.085 us; speedup vs baseline: 1.4564x; 1.1116x over previous
//
#include <hip/hip_runtime.h>
#include <hip/hip_bf16.h>

#define NN 8192      // nodes
#define NE 32768     // edges
#define FD 16        // features
#define DIM 64
#define BT 4
#define RANK 512

typedef __attribute__((ext_vector_type(8))) short bf16x8;
typedef __attribute__((ext_vector_type(4))) float f32x4;

__device__ inline unsigned short f2bf(float f) {
    union { float f; unsigned u; } c; c.f = f;
    return (unsigned short)((c.u + 0x7fffu + ((c.u >> 16) & 1u)) >> 16);
}
__device__ inline float ubf(unsigned short h) {
    union { unsigned u; float f; } c; c.u = ((unsigned)h) << 16; return c.f;
}
__device__ inline float bflo(unsigned u) { union { unsigned u; float f; } c; c.u = u << 16; return c.f; }
__device__ inline float bfhi(unsigned u) { union { unsigned u; float f; } c; c.u = u & 0xffff0000u; return c.f; }

// ================================================================ k_prep: all one-time prep fused
__global__ __launch_bounds__(256) void k_prep(
    const float* __restrict__ x, const int* __restrict__ ei, const float* __restrict__ ea,
    const float* __restrict__ W0, const float* __restrict__ b0,
    const float* __restrict__ nnW1, const float* __restrict__ nnb1,
    const float* __restrict__ W2, const float* __restrict__ Wih, const float* __restrict__ Whh,
    const float* __restrict__ root, const float* __restrict__ b2,
    const float* __restrict__ U, const float* __restrict__ V,
    float* __restrict__ s, unsigned short* __restrict__ shi, unsigned short* __restrict__ slo,
    float* __restrict__ deg, int* __restrict__ srccnt,
    float* __restrict__ h32, int* __restrict__ bond,
    unsigned short* __restrict__ w2h, unsigned short* __restrict__ w2l,
    unsigned short* __restrict__ wihh, unsigned short* __restrict__ wihl,
    unsigned short* __restrict__ whhh, unsigned short* __restrict__ whhl,
    unsigned short* __restrict__ rth, unsigned short* __restrict__ rtl,
    unsigned short* __restrict__ b2th, unsigned short* __restrict__ b2tl,
    float* __restrict__ M)
{
    int bid = blockIdx.x, tid = threadIdx.x;
    if (bid < 2048) {
        int gid = bid * 256 + tid;          // gid = n*64 + d
        int n = gid >> 6, d = gid & 63;
        const float4* xr = (const float4*)(x + (size_t)n * FD);
        const float4* wr = (const float4*)(W0 + d * FD);
        float4 x0 = xr[0], x1 = xr[1], x2 = xr[2], x3 = xr[3];
        float4 w0 = wr[0], w1 = wr[1], w2 = wr[2], w3 = wr[3];
        float acc = b0[d]
            + x0.x*w0.x + x0.y*w0.y + x0.z*w0.z + x0.w*w0.w
            + x1.x*w1.x + x1.y*w1.y + x1.z*w1.z + x1.w*w1.w
            + x2.x*w2.x + x2.y*w2.y + x2.z*w2.z + x2.w*w2.w
            + x3.x*w3.x + x3.y*w3.y + x3.z*w3.z + x3.w*w3.w;
        float sv = fmaxf(acc, 0.f);
        s[gid] = sv;
        unsigned short h = f2bf(sv);
        shi[gid] = h; slo[gid] = f2bf(sv - ubf(h));
    } else if (bid < 2176) {
        int e = (bid - 2048) * 256 + tid;
        atomicAdd(&deg[ei[NE + e]], 1.0f);
        atomicAdd(&srccnt[ei[e]], 1);
    } else if (bid < 6272) {
        int e = (bid - 2176) * 8 + (tid >> 5);
        int k = tid & 31;
        float a0 = ea[e * 4 + 0], a1 = ea[e * 4 + 1], a2 = ea[e * 4 + 2], a3 = ea[e * 4 + 3];
        float h = nnb1[k] + a0 * nnW1[k * 4 + 0] + a1 * nnW1[k * 4 + 1]
                          + a2 * nnW1[k * 4 + 2] + a3 * nnW1[k * 4 + 3];
        h32[e * 32 + k] = fmaxf(h, 0.f);
        if (k == 0) {
            int bi = 0; float bv = a0;
            if (a1 > bv) { bv = a1; bi = 1; }
            if (a2 > bv) { bv = a2; bi = 2; }
            if (a3 > bv) { bv = a3; bi = 3; }
            bond[e] = bi;
        }
    } else if (bid < 6784) {
        int gid = (bid - 6272) * 256 + tid;     // gid = col*64 + i
        int col = gid >> 6, i = gid & 63;
        float v = W2[(size_t)(i * 64 + (col >> 5)) * 32 + (col & 31)];
        unsigned short h = f2bf(v);
        w2h[gid] = h; w2l[gid] = f2bf(v - ubf(h));
    } else if (bid < 6880) {
        int gid = (bid - 6784) * 256 + tid;     // 24576 total
        if (gid < 12288) {
            float v = Wih[gid];
            unsigned short h = f2bf(v);
            wihh[gid] = h; wihl[gid] = f2bf(v - ubf(h));
        } else {
            int g = gid - 12288;
            float v = Whh[g];
            unsigned short h = f2bf(v);
            whhh[g] = h; whhl[g] = f2bf(v - ubf(h));
        }
    } else if (bid < 6896) {
        int gid = (bid - 6880) * 256 + tid;     // gid = o*64 + i
        int o = gid >> 6, i = gid & 63;
        float v = root[i * 64 + o];
        unsigned short h = f2bf(v);
        rth[gid] = h; rtl[gid] = f2bf(v - ubf(h));
    } else if (bid < 6912) {
        int gid = (bid - 6896) * 256 + tid;
        int o = gid >> 6, i = gid & 63;
        float v = b2[i * 64 + o];
        unsigned short h = f2bf(v);
        b2th[gid] = h; b2tl[gid] = f2bf(v - ubf(h));
    } else {
        __shared__ float red[4][64];
        int t = bid - 6912;
        int b = t >> 6, d = t & 63;
        int chunk = tid >> 6, dp = tid & 63;
        const float* Vp = V + ((size_t)b * DIM + d) * RANK;
        const float* Up = U + (size_t)b * RANK * DIM;
        float acc = 0.f;
        for (int r = chunk * 128; r < chunk * 128 + 128; ++r)
            acc += Vp[r] * Up[(size_t)r * DIM + dp];
        red[chunk][dp] = acc;
        __syncthreads();
        if (chunk == 0)
            M[((size_t)b * DIM + d) * DIM + dp] =
                red[0][dp] + red[1][dp] + red[2][dp] + red[3][dp];
    }
}

// ================================================================ CSR: exclusive scan of src counts
__global__ __launch_bounds__(1024) void k_scan(const int* __restrict__ cnt,
                                               int* __restrict__ start, int* __restrict__ cursor) {
    __shared__ int ls[1024];
    int tid = threadIdx.x;
    int v[8], tot = 0;
#pragma unroll
    for (int j = 0; j < 8; ++j) { v[j] = cnt[tid * 8 + j]; tot += v[j]; }
    ls[tid] = tot;
    __syncthreads();
    for (int off = 1; off < 1024; off <<= 1) {
        int t = (tid >= off) ? ls[tid - off] : 0;
        __syncthreads();
        ls[tid] += t;
        __syncthreads();
    }
    int run = ls[tid] - tot;   // exclusive base
#pragma unroll
    for (int j = 0; j < 8; ++j) {
        start[tid * 8 + j] = run; cursor[tid * 8 + j] = run; run += v[j];
    }
}

__global__ __launch_bounds__(256) void k_scatter(const int* __restrict__ ei,
                                                 int* __restrict__ cursor, int* __restrict__ eord) {
    int e = blockIdx.x * 256 + threadIdx.x;
    int pos = atomicAdd(&cursor[ei[e]], 1);
    eord[pos] = e;
}

// ================================================================ A = s @ W2 (+ cbuf = s @ b2) via split-bf16 MFMA
__global__ __launch_bounds__(256) void k_gemm_A(const unsigned short* __restrict__ sh,
                                                const unsigned short* __restrict__ sl,
                                                const unsigned short* __restrict__ wh,
                                                const unsigned short* __restrict__ wl,
                                                const unsigned short* __restrict__ b2th,
                                                const unsigned short* __restrict__ b2tl,
                                                unsigned short* __restrict__ A,
                                                float* __restrict__ cbuf) {
    int tid = threadIdx.x, wid = tid >> 6, lane = tid & 63;
    int lr = lane & 15, kg = lane >> 4;
    int m0 = blockIdx.x * 64;
    if (blockIdx.y == 8) {
        f32x4 acc[4] = {};
#pragma unroll
        for (int kb = 0; kb < 64; kb += 32) {
            size_t offA = (size_t)(m0 + wid * 16 + lr) * 64 + kb + kg * 8;
            bf16x8 ah = *(const bf16x8*)(sh + offA);
            bf16x8 al = *(const bf16x8*)(sl + offA);
#pragma unroll
            for (int ni = 0; ni < 4; ++ni) {
                size_t offB = (size_t)(ni * 16 + lr) * 64 + kb + kg * 8;
                bf16x8 bh = *(const bf16x8*)(b2th + offB);
                bf16x8 bl = *(const bf16x8*)(b2tl + offB);
                acc[ni] = __builtin_amdgcn_mfma_f32_16x16x32_bf16(ah, bh, acc[ni], 0, 0, 0);
                acc[ni] = __builtin_amdgcn_mfma_f32_16x16x32_bf16(ah, bl, acc[ni], 0, 0, 0);
                acc[ni] = __builtin_amdgcn_mfma_f32_16x16x32_bf16(al, bh, acc[ni], 0, 0, 0);
            }
        }
#pragma unroll
        for (int ni = 0; ni < 4; ++ni)
#pragma unroll
            for (int r = 0; r < 4; ++r)
                cbuf[(size_t)(m0 + wid * 16 + kg * 4 + r) * 64 + ni * 16 + lr] = acc[ni][r];
        return;
    }
    int n0 = blockIdx.y * 256 + wid * 64;
    f32x4 acc[4][4] = {};
#pragma unroll
    for (int kb = 0; kb < 64; kb += 32) {
        bf16x8 ah[4], al[4], bh[4], bl[4];
#pragma unroll
        for (int mi = 0; mi < 4; ++mi) {
            size_t off = (size_t)(m0 + mi * 16 + lr) * 64 + kb + kg * 8;
            ah[mi] = *(const bf16x8*)(sh + off);
            al[mi] = *(const bf16x8*)(sl + off);
        }
#pragma unroll
        for (int ni = 0; ni < 4; ++ni) {
            size_t off = (size_t)(n0 + ni * 16 + lr) * 64 + kb + kg * 8;
            bh[ni] = *(const bf16x8*)(wh + off);
            bl[ni] = *(const bf16x8*)(wl + off);
        }
#pragma unroll
        for (int mi = 0; mi < 4; ++mi)
#pragma unroll
            for (int ni = 0; ni < 4; ++ni) {
                acc[mi][ni] = __builtin_amdgcn_mfma_f32_16x16x32_bf16(ah[mi], bh[ni], acc[mi][ni], 0, 0, 0);
                acc[mi][ni] = __builtin_amdgcn_mfma_f32_16x16x32_bf16(ah[mi], bl[ni], acc[mi][ni], 0, 0, 0);
                acc[mi][ni] = __builtin_amdgcn_mfma_f32_16x16x32_bf16(al[mi], bh[ni], acc[mi][ni], 0, 0, 0);
            }
    }
#pragma unroll
    for (int mi = 0; mi < 4; ++mi)
#pragma unroll
        for (int r = 0; r < 4; ++r) {
            size_t row = (size_t)(m0 + mi * 16 + kg * 4 + r) * 2048;
#pragma unroll
            for (int ni = 0; ni < 4; ++ni)
                A[row + n0 + ni * 16 + lr] = f2bf(acc[mi][ni][r]);
        }
}

// ================================================================ CSR edge message + scatter
__global__ __launch_bounds__(256) void k_edge(const int* __restrict__ ei,
                                              const int* __restrict__ start,
                                              const int* __restrict__ srccnt,
                                              const int* __restrict__ eord,
                                              const float* __restrict__ h32,
                                              const unsigned short* __restrict__ A,
                                              const float* __restrict__ cbuf,
                                              float* __restrict__ agg) {
    int tid = threadIdx.x, wid = tid >> 6, o = tid & 63;
    int n = blockIdx.x * 4 + wid;
    int cnt = srccnt[n];
    if (cnt == 0) return;
    int beg = start[n];
    float cv = cbuf[(size_t)n * DIM + o];
    const uint4* Ap = (const uint4*)(A + (size_t)n * 2048 + o * 32);
    uint4 a0 = Ap[0], a1 = Ap[1], a2 = Ap[2], a3 = Ap[3];
    for (int i = beg; i < beg + cnt; ++i) {
        int e = eord[i];
        int dst = ei[NE + e];
        const float4* hp = (const float4*)(h32 + (size_t)e * 32);
        float acc = cv;
        float4 hA = hp[0], hB = hp[1];
        acc += hA.x*bflo(a0.x) + hA.y*bfhi(a0.x) + hA.z*bflo(a0.y) + hA.w*bfhi(a0.y)
             + hB.x*bflo(a0.z) + hB.y*bfhi(a0.z) + hB.z*bflo(a0.w) + hB.w*bfhi(a0.w);
        hA = hp[2]; hB = hp[3];
        acc += hA.x*bflo(a1.x) + hA.y*bfhi(a1.x) + hA.z*bflo(a1.y) + hA.w*bfhi(a1.y)
             + hB.x*bflo(a1.z) + hB.y*bfhi(a1.z) + hB.z*bflo(a1.w) + hB.w*bfhi(a1.w);
        hA = hp[4]; hB = hp[5];
        acc += hA.x*bflo(a2.x) + hA.y*bfhi(a2.x) + hA.z*bflo(a2.y) + hA.w*bfhi(a2.y)
             + hB.x*bflo(a2.z) + hB.y*bfhi(a2.z) + hB.z*bflo(a2.w) + hB.w*bfhi(a2.w);
        hA = hp[6]; hB = hp[7];
        acc += hA.x*bflo(a3.x) + hA.y*bfhi(a3.x) + hA.z*bflo(a3.y) + hA.w*bfhi(a3.y)
             + hB.x*bflo(a3.z) + hB.y*bfhi(a3.z) + hB.z*bflo(a3.w) + hB.w*bfhi(a3.w);
        atomicAdd(&agg[(size_t)dst * DIM + o], acc);
    }
}

// ================================================================ fused update, 4 waves/block (occupancy fix)
// Phase 1: wave w computes m-strip cols [w*16, w*16+16) -> hi/lo LDS.
// Phase 2: wave w computes gi strips 3w..3w+2 (A=m from LDS) and
//          gh strips 3w..3w+2 (A=s in regs) -> 16x384 f32 LDS.
// Phase 3: 256 threads GRU elementwise from LDS, coalesced global out.
__global__ __launch_bounds__(256) void k_upd(
    float* __restrict__ s, unsigned short* __restrict__ shi, unsigned short* __restrict__ slo,
    float* __restrict__ agg, const float* __restrict__ deg, const float* __restrict__ conv_b,
    const unsigned short* __restrict__ rth, const unsigned short* __restrict__ rtl,
    const unsigned short* __restrict__ wihh, const unsigned short* __restrict__ wihl,
    const unsigned short* __restrict__ whhh, const unsigned short* __restrict__ whhl,
    const float* __restrict__ bih, const float* __restrict__ bhh)
{
    __shared__ unsigned short mh_l[16 * 64];
    __shared__ unsigned short ml_l[16 * 64];
    __shared__ float gl[16 * 384];
    int tid = threadIdx.x;
    int wid = tid >> 6, lane = tid & 63;
    int lr = lane & 15, kg = lane >> 4;
    int m0 = blockIdx.x * 16;

    // s A-fragments (16 rows x K=64) — shared by phases 1 & 2
    bf16x8 sa_h[2], sa_l[2];
#pragma unroll
    for (int kb = 0; kb < 2; ++kb) {
        size_t off = (size_t)(m0 + lr) * 64 + kb * 32 + kg * 8;
        sa_h[kb] = *(const bf16x8*)(shi + off);
        sa_l[kb] = *(const bf16x8*)(slo + off);
    }

    // ---- phase 1: m strip ni = wid
    f32x4 macc = {};
#pragma unroll
    for (int kb = 0; kb < 2; ++kb) {
        size_t offB = (size_t)(wid * 16 + lr) * 64 + kb * 32 + kg * 8;
        bf16x8 bh = *(const bf16x8*)(rth + offB);
        bf16x8 bl = *(const bf16x8*)(rtl + offB);
        macc = __builtin_amdgcn_mfma_f32_16x16x32_bf16(sa_h[kb], bh, macc, 0, 0, 0);
        macc = __builtin_amdgcn_mfma_f32_16x16x32_bf16(sa_h[kb], bl, macc, 0, 0, 0);
        macc = __builtin_amdgcn_mfma_f32_16x16x32_bf16(sa_l[kb], bh, macc, 0, 0, 0);
    }
#pragma unroll
    for (int r = 0; r < 4; ++r) {
        int row = m0 + kg * 4 + r;
        float inv = 1.f / fmaxf(deg[row], 1.f);
        int col = wid * 16 + lr;
        size_t idx = (size_t)row * 64 + col;
        float v = macc[r] + agg[idx] * inv + conv_b[col];
        agg[idx] = 0.f;                       // self-zero for next iteration
        v = fmaxf(v, 0.f);
        unsigned short h = f2bf(v);
        int loff = (kg * 4 + r) * 64 + col;
        mh_l[loff] = h; ml_l[loff] = f2bf(v - ubf(h));
    }
    __syncthreads();

    // ---- phase 2: m A-frags from LDS, 3 gi + 3 gh strips per wave
    bf16x8 ma_h[2], ma_l[2];
#pragma unroll
    for (int kb = 0; kb < 2; ++kb) {
        int loff = lr * 64 + kb * 32 + kg * 8;
        ma_h[kb] = *(const bf16x8*)(mh_l + loff);
        ma_l[kb] = *(const bf16x8*)(ml_l + loff);
    }
    f32x4 gacc[3] = {}, hacc[3] = {};
#pragma unroll
    for (int kb = 0; kb < 2; ++kb)
#pragma unroll
        for (int j = 0; j < 3; ++j) {
            int ni = wid * 3 + j;            // 0..11
            size_t offB = (size_t)(ni * 16 + lr) * 64 + kb * 32 + kg * 8;
            bf16x8 bh = *(const bf16x8*)(wihh + offB);
            bf16x8 bl = *(const bf16x8*)(wihl + offB);
            gacc[j] = __builtin_amdgcn_mfma_f32_16x16x32_bf16(ma_h[kb], bh, gacc[j], 0, 0, 0);
            gacc[j] = __builtin_amdgcn_mfma_f32_16x16x32_bf16(ma_h[kb], bl, gacc[j], 0, 0, 0);
            gacc[j] = __builtin_amdgcn_mfma_f32_16x16x32_bf16(ma_l[kb], bh, gacc[j], 0, 0, 0);
            bf16x8 ch = *(const bf16x8*)(whhh + offB);
            bf16x8 cl = *(const bf16x8*)(whhl + offB);
            hacc[j] = __builtin_amdgcn_mfma_f32_16x16x32_bf16(sa_h[kb], ch, hacc[j], 0, 0, 0);
            hacc[j] = __builtin_amdgcn_mfma_f32_16x16x32_bf16(sa_h[kb], cl, hacc[j], 0, 0, 0);
            hacc[j] = __builtin_amdgcn_mfma_f32_16x16x32_bf16(sa_l[kb], ch, hacc[j], 0, 0, 0);
        }
#pragma unroll
    for (int j = 0; j < 3; ++j)
#pragma unroll
        for (int r = 0; r < 4; ++r) {
            int row = kg * 4 + r;
            int col = (wid * 3 + j) * 16 + lr;      // 0..191
            gl[row * 384 + col] = gacc[j][r];
            gl[row * 384 + 192 + col] = hacc[j][r];
        }
    __syncthreads();

    // ---- phase 3: GRU elementwise
#pragma unroll
    for (int k = 0; k < 4; ++k) {
        int item = tid + k * 256;           // 0..1023
        int row = item >> 6, d = item & 63;
        size_t idx = (size_t)(m0 + row) * 64 + d;
        const float* gr = gl + row * 384;
        float ir = gr[d], iz = gr[64 + d], in_ = gr[128 + d];
        float hr_ = gr[192 + d], hz = gr[256 + d], hn = gr[320 + d];
        float hv = s[idx];
        float rg = 1.f / (1.f + expf(-(ir + bih[d] + hr_ + bhh[d])));
        float z  = 1.f / (1.f + expf(-(iz + bih[64 + d] + hz + bhh[64 + d])));
        float nv = tanhf(in_ + bih[128 + d] + rg * (hn + bhh[128 + d]));
        float nh = (1.f - z) * nv + z * hv;
        s[idx] = nh;
        unsigned short hb = f2bf(nh);
        shi[idx] = hb; slo[idx] = f2bf(nh - ubf(hb));
    }
}

// ================================================================ out_edges + out_combine
__global__ __launch_bounds__(256) void k_edges_out(const float* __restrict__ s,
                                                   const float* __restrict__ x,
                                                   const float* __restrict__ W1l,
                                                   const float* __restrict__ b1l,
                                                   const float* __restrict__ WUp,
                                                   const float* __restrict__ bUp,
                                                   float* __restrict__ oe,
                                                   float* __restrict__ oc) {
    __shared__ float sm_s[4][64];
    __shared__ float sm_oe[4][4];
    int tid = threadIdx.x, w = tid >> 6, lane = tid & 63;
    int node = blockIdx.x * 4 + w;
    float sv = s[(size_t)node * DIM + lane];
    sm_s[w][lane] = sv;
    __syncthreads();
    if (lane < 4) {
        float acc = b1l[lane];
        for (int i = 0; i < 64; ++i) acc += sm_s[w][i] * W1l[lane * 64 + i];
        acc = fmaxf(acc, 0.f);
        sm_oe[w][lane] = acc;
        oe[(size_t)node * 4 + lane] = acc;
    }
    __syncthreads();
    float ocv;
    if (x[(size_t)node * FD] == 2.0f) {
        ocv = bUp[lane];
#pragma unroll
        for (int t = 0; t < 4; ++t) ocv += sm_oe[w][t] * WUp[lane * 4 + t];
    } else {
        ocv = sv;
    }
    oc[(size_t)node * DIM + lane] = ocv;
}

// ================================================================ FGNet edge: me = oc[src] @ M[bond], scatter
__global__ __launch_bounds__(256) void k_fgedge(const int* __restrict__ ei,
                                                const int* __restrict__ bond,
                                                const float* __restrict__ oc,
                                                const float* __restrict__ M,
                                                float* __restrict__ fg_agg) {
    __shared__ float so[4][64];
    int tid = threadIdx.x, w = tid >> 6, lane = tid & 63;
    int e = blockIdx.x * 4 + w;
    int src = ei[e], dst = ei[NE + e];
    int b = bond[e];
    so[w][lane] = oc[(size_t)src * DIM + lane];
    __syncthreads();
    float acc = 0.f;
    const float* Mp = M + b * DIM * DIM;
    for (int d = 0; d < 64; ++d) acc += so[w][d] * Mp[d * 64 + lane];
    atomicAdd(&fg_agg[(size_t)dst * DIM + lane], acc);
}

// ================================================================ final: msg_f -> msg_to_edge -> out_edges -> log_softmax
__global__ __launch_bounds__(256) void k_final(const float* __restrict__ fg_agg,
                                               const float* __restrict__ deg,
                                               const float* __restrict__ oe,
                                               const float* __restrict__ WDown,
                                               const float* __restrict__ bDown,
                                               const float* __restrict__ weight_e,
                                               const float* __restrict__ linWe,
                                               const float* __restrict__ linbe,
                                               float* __restrict__ out) {
    int tid = threadIdx.x, w = tid >> 6, lane = tid & 63;
    int node = blockIdx.x * 4 + w;
    float degc = fmaxf(deg[node], 1.f);
    float mf = fmaxf(fg_agg[(size_t)node * DIM + lane] / degc, 0.f);
    float mte[4];
#pragma unroll
    for (int t = 0; t < 4; ++t) {
        float p = mf * WDown[t * 64 + lane];
#pragma unroll
        for (int off = 32; off; off >>= 1) p += __shfl_xor(p, off);
        mte[t] = p + bDown[t];
    }
    float val[4];
    float mx = -1e30f;
#pragma unroll
    for (int t = 0; t < 4; ++t) {
        float acc = linbe[t];
#pragma unroll
        for (int t2 = 0; t2 < 4; ++t2) acc += weight_e[t2] * mte[t2] * linWe[t * 4 + t2];
        val[t] = oe[(size_t)node * 4 + t] + fmaxf(acc, 0.f);
        mx = fmaxf(mx, val[t]);
    }
    float lse = 0.f;
#pragma unroll
    for (int t = 0; t < 4; ++t) lse += expf(val[t] - mx);
    lse = logf(lse);
    if (lane < 4) out[(size_t)node * 4 + lane] = val[lane] - mx - lse;
}

// ================================================================ host
extern "C" void kernel_launch(void* const* d_in, const int* in_sizes, int n_in,
                              void* d_out, int out_size, void* d_ws, size_t ws_size,
                              hipStream_t stream) {
    const float* x       = (const float*)d_in[0];
    const int*   ei      = (const int*)  d_in[1];
    const float* ea      = (const float*)d_in[2];
    const float* W0      = (const float*)d_in[3];
    const float* b0      = (const float*)d_in[4];
    const float* nnW1    = (const float*)d_in[5];
    const float* nnb1    = (const float*)d_in[6];
    const float* nnW2    = (const float*)d_in[7];
    const float* nnb2    = (const float*)d_in[8];
    const float* root    = (const float*)d_in[9];
    const float* conv_b  = (const float*)d_in[10];
    const float* Wih     = (const float*)d_in[11];
    const float* Whh     = (const float*)d_in[12];
    const float* bih     = (const float*)d_in[13];
    const float* bhh     = (const float*)d_in[14];
    const float* W1l     = (const float*)d_in[15];
    const float* b1l     = (const float*)d_in[16];
    const float* WUp     = (const float*)d_in[17];
    const float* bUp     = (const float*)d_in[18];
    const float* WDown   = (const float*)d_in[19];
    const float* bDown   = (const float*)d_in[20];
    const float* U       = (const float*)d_in[21];
    const float* V       = (const float*)d_in[22];
    const float* weight_e= (const float*)d_in[26];
    const float* linWe   = (const float*)d_in[27];
    const float* linbe   = (const float*)d_in[28];
    float* out = (float*)d_out;

    char* ws = (char*)d_ws;
    size_t off = 0;
    auto alloc = [&](size_t bytes) { size_t o = off; off = (off + bytes + 255) & ~(size_t)255; return o; };
    float* deg    = (float*)(ws + alloc((size_t)NN * 4));
    int*   srccnt = (int*)  (ws + alloc((size_t)NN * 4));            // adjacent to deg (one memset)
    float* agg    = (float*)(ws + alloc((size_t)NN * DIM * 4));
    float* fg_agg = (float*)(ws + alloc((size_t)NN * DIM * 4));      // adjacent to agg (one memset)
    float* s      = (float*)(ws + alloc((size_t)NN * DIM * 4));
    unsigned short* shi = (unsigned short*)(ws + alloc((size_t)NN * DIM * 2));
    unsigned short* slo = (unsigned short*)(ws + alloc((size_t)NN * DIM * 2));
    float* cbuf   = (float*)(ws + alloc((size_t)NN * DIM * 4));
    float* h32    = (float*)(ws + alloc((size_t)NE * 32 * 4));
    int*   bond   = (int*)  (ws + alloc((size_t)NE * 4));
    int*   startp = (int*)  (ws + alloc((size_t)NN * 4));
    int*   cursor = (int*)  (ws + alloc((size_t)NN * 4));
    int*   eord   = (int*)  (ws + alloc((size_t)NE * 4));
    float* oe     = (float*)(ws + alloc((size_t)NN * 4 * 4));
    float* oc     = (float*)(ws + alloc((size_t)NN * DIM * 4));
    float* Mbuf   = (float*)(ws + alloc((size_t)BT * DIM * DIM * 4));
    unsigned short* w2h = (unsigned short*)(ws + alloc((size_t)2048 * 64 * 2));
    unsigned short* w2l = (unsigned short*)(ws + alloc((size_t)2048 * 64 * 2));
    unsigned short* wihh = (unsigned short*)(ws + alloc((size_t)192 * 64 * 2));
    unsigned short* wihl = (unsigned short*)(ws + alloc((size_t)192 * 64 * 2));
    unsigned short* whhh = (unsigned short*)(ws + alloc((size_t)192 * 64 * 2));
    unsigned short* whhl = (unsigned short*)(ws + alloc((size_t)192 * 64 * 2));
    unsigned short* rth  = (unsigned short*)(ws + alloc((size_t)64 * 64 * 2));
    unsigned short* rtl  = (unsigned short*)(ws + alloc((size_t)64 * 64 * 2));
    unsigned short* b2th = (unsigned short*)(ws + alloc((size_t)64 * 64 * 2));
    unsigned short* b2tl = (unsigned short*)(ws + alloc((size_t)64 * 64 * 2));
    unsigned short* Abuf = (unsigned short*)(ws + alloc((size_t)NN * 2048 * 2));
    (void)n_in; (void)in_sizes; (void)out_size; (void)ws_size;

    hipMemsetAsync(deg, 0, (size_t)2 * NN * 4, stream);              // deg + srccnt
    hipMemsetAsync(agg, 0, (size_t)2 * NN * DIM * 4, stream);        // agg + fg_agg

    k_prep<<<7168, 256, 0, stream>>>(x, ei, ea, W0, b0, nnW1, nnb1,
                                     nnW2, Wih, Whh, root, nnb2, U, V,
                                     s, shi, slo, deg, srccnt, h32, bond,
                                     w2h, w2l, wihh, wihl, whhh, whhl,
                                     rth, rtl, b2th, b2tl, Mbuf);
    k_scan<<<1, 1024, 0, stream>>>(srccnt, startp, cursor);
    k_scatter<<<NE / 256, 256, 0, stream>>>(ei, cursor, eord);

    for (int it = 0; it < 3; ++it) {
        k_gemm_A<<<dim3(NN / 64, 9), 256, 0, stream>>>(shi, slo, w2h, w2l, b2th, b2tl,
                                                       Abuf, cbuf);
        k_edge<<<NN / 4, 256, 0, stream>>>(ei, startp, srccnt, eord, h32, Abuf, cbuf, agg);
        k_upd<<<NN / 16, 256, 0, stream>>>(s, shi, slo, agg, deg, conv_b,
                                           rth, rtl, wihh, wihl, whhh, whhl, bih, bhh);
    }

    k_edges_out<<<NN / 4, 256, 0, stream>>>(s, x, W1l, b1l, WUp, bUp, oe, oc);
    k_fgedge<<<NE / 4, 256, 0, stream>>>(ei, bond, oc, Mbuf, fg_agg);
    k_final<<<NN / 4, 256, 0, stream>>>(fg_agg, deg, oe, WDown, bDown, weight_e, linWe, linbe, out);
}